// Round 1
// baseline (535.129 us; speedup 1.0000x reference)
//
#include <hip/hip_runtime.h>
#include <stdint.h>

typedef __attribute__((ext_vector_type(8))) short bf16x8;
typedef __attribute__((ext_vector_type(4))) float f32x4;

#define EPSB 1e-5f

// ---------------- workspace byte offsets ----------------
#define W0TE_B   0u          // [64][192] bf16, k = tap*64 + c   (block0 tconv, BN-folded)
#define W1SB_B   24576u      // [128][64] bf16                    (block1 spatial, BN-folded)
#define W1E_B    40960u      // [2][128][192] bf16, k = tap*64 + c_loc, c = h*64 + c_loc
#define W1R_B    139264u     // [128][64] bf16                    (block1 residual, BN-folded)
#define PROJT_B  155648u     // [128][128] bf16, [n][e] = proj_w[e][n]
#define WS0F_B   188416u     // [64][4] f32  block0 spatial w (K=3 pad 4)
#define WR0F_B   189440u     // [64][4] f32  block0 residual w
#define BS0F_B   190464u     // [64] f32  block0 spatial bias (BN-folded)
#define CB0F_B   190720u     // [64] f32  block0 combined tconv+resid bias
#define BS1F_B   190976u     // [128] f32
#define CB1F_B   191488u     // [128] f32
#define Y0_B     192512u     // [chunk][2048][17][64] bf16
#define Y0_PERB  4456448ull  // bytes per batch of y0

__device__ __forceinline__ float bf2f(unsigned int u16) {
    union { unsigned int i; float f; } v; v.i = u16 << 16; return v.f;
}
__device__ __forceinline__ unsigned short f2bf(float f) {
    unsigned int x = __float_as_uint(f);
    x = x + 0x7fffu + ((x >> 16) & 1u);   // RNE
    return (unsigned short)(x >> 16);
}

struct PrepArgs {
    const float *sw0,*sb0,*sg0,*sbb0,*sm0,*sv0;
    const float *tw0,*tb0,*tg0,*tbb0,*tm0,*tv0;
    const float *rw0,*rb0,*rg0,*rbb0,*rm0,*rv0;
    const float *sw1,*sb1,*sg1,*sbb1,*sm1,*sv1;
    const float *tw1,*tb1,*tg1,*tbb1,*tm1,*tv1;
    const float *rw1,*rb1,*rg1,*rbb1,*rm1,*rv1;
    const float *projw;
    unsigned char* ws;
};

// Fold BN (inference) into conv weights: BN(conv(x,W,b)) = conv(x, s*W, s*(b-m)+beta)
__global__ void prep_kernel(PrepArgs a) {
    const int g = blockIdx.x * 256 + threadIdx.x;
    unsigned short* W0TE  = (unsigned short*)(a.ws + W0TE_B);
    unsigned short* W1SBp = (unsigned short*)(a.ws + W1SB_B);
    unsigned short* W1Ep  = (unsigned short*)(a.ws + W1E_B);
    unsigned short* W1Rp  = (unsigned short*)(a.ws + W1R_B);
    unsigned short* PROJT = (unsigned short*)(a.ws + PROJT_B);
    float* WS0F = (float*)(a.ws + WS0F_B);
    float* WR0F = (float*)(a.ws + WR0F_B);
    float* BS0F = (float*)(a.ws + BS0F_B);
    float* CB0F = (float*)(a.ws + CB0F_B);
    float* BS1F = (float*)(a.ws + BS1F_B);
    float* CB1F = (float*)(a.ws + CB1F_B);

    if (g < 64) {
        int o = g;
        float scs = a.sg0[o] / sqrtf(a.sv0[o] + EPSB);
        BS0F[o] = scs * (a.sb0[o] - a.sm0[o]) + a.sbb0[o];
        for (int c = 0; c < 4; c++) WS0F[o*4+c] = (c < 3) ? scs * a.sw0[o*3+c] : 0.f;
        float tct = a.tg0[o] / sqrtf(a.tv0[o] + EPSB);
        float rcr = a.rg0[o] / sqrtf(a.rv0[o] + EPSB);
        CB0F[o] = tct * (a.tb0[o] - a.tm0[o]) + a.tbb0[o]
                + rcr * (a.rb0[o] - a.rm0[o]) + a.rbb0[o];
        for (int c = 0; c < 4; c++) WR0F[o*4+c] = (c < 3) ? rcr * a.rw0[o*3+c] : 0.f;
    } else if (g < 192) {
        int o = g - 64;
        float scs = a.sg1[o] / sqrtf(a.sv1[o] + EPSB);
        BS1F[o] = scs * (a.sb1[o] - a.sm1[o]) + a.sbb1[o];
        float tct = a.tg1[o] / sqrtf(a.tv1[o] + EPSB);
        float rcr = a.rg1[o] / sqrtf(a.rv1[o] + EPSB);
        CB1F[o] = tct * (a.tb1[o] - a.tm1[o]) + a.tbb1[o]
                + rcr * (a.rb1[o] - a.rm1[o]) + a.rbb1[o];
    } else if (g < 12480) {                   // W0TE: 64*192
        int idx = g - 192;
        int o = idx / 192, k = idx % 192, tap = k >> 6, c = k & 63;
        float tct = a.tg0[o] / sqrtf(a.tv0[o] + EPSB);
        W0TE[o*192 + k] = f2bf(tct * a.tw0[(o*64 + c)*3 + tap]);
    } else if (g < 20672) {                   // W1SB: 128*64
        int idx = g - 12480;
        int o = idx >> 6, c = idx & 63;
        float scs = a.sg1[o] / sqrtf(a.sv1[o] + EPSB);
        W1SBp[o*64 + c] = f2bf(scs * a.sw1[o*64 + c]);
    } else if (g < 69824) {                   // W1E: 2*128*192
        int idx = g - 20672;
        int h = idx / 24576, r = idx % 24576;
        int o = r / 192, k = r % 192, tap = k >> 6, c = (h << 6) + (k & 63);
        float tct = a.tg1[o] / sqrtf(a.tv1[o] + EPSB);
        W1Ep[(h*128 + o)*192 + k] = f2bf(tct * a.tw1[(o*128 + c)*3 + tap]);
    } else if (g < 78016) {                   // W1R: 128*64
        int idx = g - 69824;
        int o = idx >> 6, c = idx & 63;
        float rcr = a.rg1[o] / sqrtf(a.rv1[o] + EPSB);
        W1Rp[o*64 + c] = f2bf(rcr * a.rw1[o*64 + c]);
    } else if (g < 94400) {                   // PROJT: 128*128 transposed
        int idx = g - 78016;
        int n = idx >> 7, e = idx & 127;
        PROJT[n*128 + e] = f2bf(a.projw[e*128 + n]);
    }
}

// ---------------- block 0: 3 -> 64 ----------------
// per block: batch b, 16 timesteps. s0 (spatial branch) via VALU (K=3),
// tconv via MFMA GEMM M=272 N=64 K=192, residual via VALU epilogue.
__launch_bounds__(256, 2)
__global__ void b0_kernel(const float* __restrict__ x, const float* __restrict__ adj,
                          unsigned char* __restrict__ ws, int b0base) {
    __shared__ float xt[918];                 // [3][306] f32, halo rows (t0-1..t0+16)
    __shared__ float xg[918];                 // graph-conv of xt
    __shared__ float adjs[289];
    __shared__ float Ws0s[256];
    __shared__ float Wr0s[256];
    __shared__ float bs0s[64];
    __shared__ float cb0s[64];
    __shared__ unsigned short s0[22032];      // [306][72] bf16 (144B rows, odd*16B)

    const int tid = threadIdx.x;
    const int b_loc = blockIdx.x >> 7;
    const int b = b0base + b_loc;
    const int t0 = (blockIdx.x & 127) << 4;

    for (int i = tid; i < 289; i += 256) adjs[i] = adj[i];
    Ws0s[tid] = ((const float*)(ws + WS0F_B))[tid];
    Wr0s[tid] = ((const float*)(ws + WR0F_B))[tid];
    if (tid < 64) {
        bs0s[tid] = ((const float*)(ws + BS0F_B))[tid];
        cb0s[tid] = ((const float*)(ws + CB0F_B))[tid];
    }
    for (int i = tid; i < 918; i += 256) {
        int c = i / 306, p = i - c*306;
        int t = p / 17, j = p - t*17;
        int gt = t0 + t - 1;
        float v = 0.f;
        if (gt >= 0 && gt < 2048) v = x[((size_t)(b*3 + c)*2048 + gt)*17 + j];
        xt[i] = v;
    }
    __syncthreads();
    for (int i = tid; i < 918; i += 256) {    // xg = xt . adj (over J)
        int p = i % 306;
        int j = p % 17;
        const float* xr = &xt[i - j];
        float acc = 0.f;
        for (int k = 0; k < 17; k++) acc += xr[k] * adjs[k*17 + j];
        xg[i] = acc;
    }
    __syncthreads();
    {   // s0 = relu(conv1x1(xg)) bf16; zero rows outside global T (conv zero-pad!)
        const int psub = tid >> 4, o0 = (tid & 15) << 2;
        for (int pass = 0; pass < 20; pass++) {
            int p = pass*16 + psub;
            if (p < 306) {
                int gt = t0 + p/17 - 1;
                uint2 pk;
                if (gt >= 0 && gt < 2048) {
                    float a0 = xg[p], a1 = xg[306+p], a2 = xg[612+p];
                    float v0 = fmaxf(bs0s[o0]   + Ws0s[(o0  )*4]*a0 + Ws0s[(o0  )*4+1]*a1 + Ws0s[(o0  )*4+2]*a2, 0.f);
                    float v1 = fmaxf(bs0s[o0+1] + Ws0s[(o0+1)*4]*a0 + Ws0s[(o0+1)*4+1]*a1 + Ws0s[(o0+1)*4+2]*a2, 0.f);
                    float v2 = fmaxf(bs0s[o0+2] + Ws0s[(o0+2)*4]*a0 + Ws0s[(o0+2)*4+1]*a1 + Ws0s[(o0+2)*4+2]*a2, 0.f);
                    float v3 = fmaxf(bs0s[o0+3] + Ws0s[(o0+3)*4]*a0 + Ws0s[(o0+3)*4+1]*a1 + Ws0s[(o0+3)*4+2]*a2, 0.f);
                    pk.x = (unsigned)f2bf(v0) | ((unsigned)f2bf(v1) << 16);
                    pk.y = (unsigned)f2bf(v2) | ((unsigned)f2bf(v3) << 16);
                } else { pk.x = 0u; pk.y = 0u; }
                *(uint2*)&s0[p*72 + o0] = pk;
            }
        }
    }
    __syncthreads();
    {   // tconv GEMM + residual epilogue -> y0 (bf16, [b][t][j][c])
        const unsigned short* W0TE = (const unsigned short*)(ws + W0TE_B);
        unsigned short* Y0 = (unsigned short*)(ws + Y0_B);
        const int w = tid >> 6, l = tid & 63, lr = l & 15, lg = l >> 4;
        const int n = w*16 + lr;              // wave w owns N-block w
        bf16x8 bfr[6];
        #pragma unroll
        for (int ks = 0; ks < 6; ks++)
            bfr[ks] = *(const bf16x8*)&W0TE[n*192 + ks*32 + lg*8];
        const float wr0 = Wr0s[n*4], wr1 = Wr0s[n*4+1], wr2 = Wr0s[n*4+2];
        const float cbn = cb0s[n];
        for (int mb = 0; mb < 17; mb++) {
            const int ra = mb*16 + lr;        // A row = center position index
            f32x4 acc = {0.f, 0.f, 0.f, 0.f};
            #pragma unroll
            for (int ks = 0; ks < 6; ks++) {
                const int tap = ks >> 1;
                const int c0 = ((ks & 1) << 5) + lg*8;
                acc = __builtin_amdgcn_mfma_f32_16x16x32_bf16(
                    *(const bf16x8*)&s0[(ra + tap*17)*72 + c0], bfr[ks], acc, 0, 0, 0);
            }
            const int mbase = mb*16 + lg*4;
            #pragma unroll
            for (int i = 0; i < 4; i++) {
                const int m = mbase + i;
                const int t = m/17, j = m - t*17;
                float v = acc[i] + cbn
                        + wr0*xt[m+17] + wr1*xt[306 + m+17] + wr2*xt[612 + m+17];
                v = fmaxf(v, 0.f);
                Y0[(((size_t)b_loc*2048 + (t0 + t))*17 + j)*64 + n] = f2bf(v);
            }
        }
    }
}

// ---------------- block 1: 64 -> 128, + mean over J + projection ----------------
// per block: batch b, 8 timesteps (center M=136, halo rows 170).
__launch_bounds__(256, 2)
__global__ void b1_kernel(const float* __restrict__ adj,
                          const float* __restrict__ projb,
                          unsigned char* __restrict__ ws,
                          float* __restrict__ outp, int b0base) {
    __shared__ __align__(16) unsigned char smem[55376];
    unsigned short* buf0  = (unsigned short*)(smem);           // y0 tile, later s1 half
    unsigned short* ygs   = (unsigned short*)(smem + 24480);   // graph-conv(y0)
    float* adjs  = (float*)(smem + 48960);
    float* cb1s  = (float*)(smem + 50116);
    float* bs1s  = (float*)(smem + 50628);
    float* means = (float*)(smem + 51140);                     // [8][132] f32
    unsigned short* y1b   = (unsigned short*)(smem);           // [144][136] bf16 (alias)
    unsigned short* projL = (unsigned short*)(smem + 39168);   // [32][136] bf16 (alias)

    const int tid = threadIdx.x;
    const int b_loc = blockIdx.x >> 8;
    const int b = b0base + b_loc;
    const int t0 = (blockIdx.x & 255) << 3;

    const unsigned short* Y0    = (const unsigned short*)(ws + Y0_B);
    const unsigned short* W1SBp = (const unsigned short*)(ws + W1SB_B);
    const unsigned short* W1Ep  = (const unsigned short*)(ws + W1E_B);
    const unsigned short* W1Rp  = (const unsigned short*)(ws + W1R_B);
    const unsigned short* PROJT = (const unsigned short*)(ws + PROJT_B);

    for (int i = tid; i < 289; i += 256) adjs[i] = adj[i];
    if (tid < 128) {
        cb1s[tid] = ((const float*)(ws + CB1F_B))[tid];
        bs1s[tid] = ((const float*)(ws + BS1F_B))[tid];
    }
    for (int i = tid; i < 1360; i += 256) {   // y0 halo tile -> LDS (zero beyond T)
        int p = i >> 3, seg = (i & 7) << 3;
        int th = p / 17, j = p - th*17;
        int gt = t0 - 1 + th;
        float4 v = {0.f, 0.f, 0.f, 0.f};
        if (gt >= 0 && gt < 2048)
            v = *(const float4*)&Y0[(((size_t)b_loc*2048 + gt)*17 + j)*64 + seg];
        *(float4*)&buf0[p*72 + seg] = v;
    }
    __syncthreads();

    const int w = tid >> 6, l = tid & 63, lr = l & 15, lg = l >> 4;

    f32x4 tacc[2][9];
    #pragma unroll
    for (int a = 0; a < 2; a++)
        #pragma unroll
        for (int m = 0; m < 9; m++) tacc[a][m] = (f32x4){0.f, 0.f, 0.f, 0.f};

    // residual GEMM first (K=64, frees y0 buffer for s1)
    #pragma unroll
    for (int nbi = 0; nbi < 2; nbi++) {
        const int n = (w + nbi*4)*16 + lr;
        bf16x8 rb0 = *(const bf16x8*)&W1Rp[n*64 + lg*8];
        bf16x8 rb1 = *(const bf16x8*)&W1Rp[n*64 + 32 + lg*8];
        #pragma unroll
        for (int mb = 0; mb < 9; mb++) {
            const int row = mb*16 + lr + 17;  // center halo row (<=160)
            f32x4 acc = tacc[nbi][mb];
            acc = __builtin_amdgcn_mfma_f32_16x16x32_bf16(*(const bf16x8*)&buf0[row*72 + lg*8],      rb0, acc, 0, 0, 0);
            acc = __builtin_amdgcn_mfma_f32_16x16x32_bf16(*(const bf16x8*)&buf0[row*72 + 32 + lg*8], rb1, acc, 0, 0, 0);
            tacc[nbi][mb] = acc;
        }
    }

    {   // graph conv: ygs[p][c] = sum_k y0[t][k][c] * adj[k][j(p)]
        const int psub = tid >> 4, c0 = (tid & 15) << 2;
        for (int pass = 0; pass < 11; pass++) {
            int p = pass*16 + psub;
            if (p < 170) {
                int j = p % 17; int rb = p - j;
                float a0=0.f, a1=0.f, a2=0.f, a3=0.f;
                for (int k = 0; k < 17; k++) {
                    float av = adjs[k*17 + j];
                    uint2 u = *(const uint2*)&buf0[(rb + k)*72 + c0];
                    a0 += av * bf2f(u.x & 0xffffu);
                    a1 += av * bf2f(u.x >> 16);
                    a2 += av * bf2f(u.y & 0xffffu);
                    a3 += av * bf2f(u.y >> 16);
                }
                uint2 o;
                o.x = (unsigned)f2bf(a0) | ((unsigned)f2bf(a1) << 16);
                o.y = (unsigned)f2bf(a2) | ((unsigned)f2bf(a3) << 16);
                *(uint2*)&ygs[p*72 + c0] = o;
            }
        }
    }
    __syncthreads();

    for (int h = 0; h < 2; h++) {
        {   // s1 half: relu(W1s . yg + b) -> buf0 (zero rows beyond global T)
            const int nloc = w*16 + lr;
            const int ng = (h << 6) + nloc;
            bf16x8 sb0 = *(const bf16x8*)&W1SBp[ng*64 + lg*8];
            bf16x8 sb1 = *(const bf16x8*)&W1SBp[ng*64 + 32 + lg*8];
            const float bias = bs1s[ng];
            for (int mb = 0; mb < 11; mb++) {
                int ra = mb*16 + lr; if (ra > 169) ra = 169;
                f32x4 sa = {0.f, 0.f, 0.f, 0.f};
                sa = __builtin_amdgcn_mfma_f32_16x16x32_bf16(*(const bf16x8*)&ygs[ra*72 + lg*8],      sb0, sa, 0, 0, 0);
                sa = __builtin_amdgcn_mfma_f32_16x16x32_bf16(*(const bf16x8*)&ygs[ra*72 + 32 + lg*8], sb1, sa, 0, 0, 0);
                const int mbase = mb*16 + lg*4;
                #pragma unroll
                for (int i = 0; i < 4; i++) {
                    int m = mbase + i;
                    if (m < 170) {
                        int gt = t0 - 1 + m/17;
                        float v = 0.f;
                        if (gt >= 0 && gt < 2048) v = fmaxf(sa[i] + bias, 0.f);
                        buf0[m*72 + nloc] = f2bf(v);
                    }
                }
            }
        }
        __syncthreads();
        // temporal conv partial GEMM (K=192 for this half)
        #pragma unroll
        for (int nbi = 0; nbi < 2; nbi++) {
            const int n = (w + nbi*4)*16 + lr;
            bf16x8 bfr[6];
            #pragma unroll
            for (int ks = 0; ks < 6; ks++)
                bfr[ks] = *(const bf16x8*)&W1Ep[(h*128 + n)*192 + ks*32 + lg*8];
            #pragma unroll
            for (int mb = 0; mb < 9; mb++) {
                const int ma = mb*16 + lr;
                f32x4 acc = tacc[nbi][mb];
                #pragma unroll
                for (int ks = 0; ks < 6; ks++) {
                    const int tap = ks >> 1;
                    const int c0 = ((ks & 1) << 5) + lg*8;
                    int row = ma + tap*17; if (row > 169) row = 169;
                    acc = __builtin_amdgcn_mfma_f32_16x16x32_bf16(
                        *(const bf16x8*)&buf0[row*72 + c0], bfr[ks], acc, 0, 0, 0);
                }
                tacc[nbi][mb] = acc;
            }
        }
        __syncthreads();
    }

    // y1 = relu(tconv + resid + bias) -> y1b (bf16)
    #pragma unroll
    for (int nbi = 0; nbi < 2; nbi++) {
        const int n = (w + nbi*4)*16 + lr;
        const float cb = cb1s[n];
        #pragma unroll
        for (int mb = 0; mb < 9; mb++) {
            const int mbase = mb*16 + lg*4;
            #pragma unroll
            for (int i = 0; i < 4; i++) {
                int m = mbase + i;
                if (m < 136) y1b[m*136 + n] = f2bf(fmaxf(tacc[nbi][mb][i] + cb, 0.f));
            }
        }
    }
    __syncthreads();

    {   // mean over J
        const int t = tid >> 5, n4 = (tid & 31) << 2;
        float m0=0.f, m1=0.f, m2=0.f, m3=0.f;
        for (int j = 0; j < 17; j++) {
            uint2 u = *(const uint2*)&y1b[(t*17 + j)*136 + n4];
            m0 += bf2f(u.x & 0xffffu); m1 += bf2f(u.x >> 16);
            m2 += bf2f(u.y & 0xffffu); m3 += bf2f(u.y >> 16);
        }
        const float s = 1.f / 17.f;
        means[t*132 + n4]     = m0*s; means[t*132 + n4 + 1] = m1*s;
        means[t*132 + n4 + 2] = m2*s; means[t*132 + n4 + 3] = m3*s;
    }
    __syncthreads();

    {   // projection: out[t][e] = sum_n mean[t][n] * proj_w[e][n] + proj_b[e]
        const int t = tid >> 5, e0 = (tid & 31) << 2;
        float o0=0.f, o1=0.f, o2=0.f, o3=0.f;
        for (int nc = 0; nc < 4; nc++) {
            {   // stage 32 rows of projT into LDS
                const int r = tid >> 3, cseg = (tid & 7) << 4;
                const unsigned short* src = &PROJT[(nc*32 + r)*128 + cseg];
                *(float4*)&projL[r*136 + cseg]     = *(const float4*)src;
                *(float4*)&projL[r*136 + cseg + 8] = *(const float4*)(src + 8);
            }
            __syncthreads();
            #pragma unroll
            for (int k = 0; k < 32; k++) {
                const float mv = means[t*132 + (nc << 5) + k];
                uint2 u = *(const uint2*)&projL[k*136 + e0];
                o0 += mv * bf2f(u.x & 0xffffu); o1 += mv * bf2f(u.x >> 16);
                o2 += mv * bf2f(u.y & 0xffffu); o3 += mv * bf2f(u.y >> 16);
            }
            __syncthreads();
        }
        float4 pb = *(const float4*)&projb[e0];
        float4 r; r.x = o0 + pb.x; r.y = o1 + pb.y; r.z = o2 + pb.z; r.w = o3 + pb.w;
        *(float4*)&outp[((size_t)b*2048 + t0 + t)*128 + e0] = r;
    }
}

extern "C" void kernel_launch(void* const* d_in, const int* in_sizes, int n_in,
                              void* d_out, int out_size, void* d_ws, size_t ws_size,
                              hipStream_t stream) {
    const float* x     = (const float*)d_in[0];
    const float* adj   = (const float*)d_in[1];
    const float* projb = (const float*)d_in[39];
    unsigned char* ws  = (unsigned char*)d_ws;

    PrepArgs pa;
    pa.sw0 = (const float*)d_in[2];  pa.sb0  = (const float*)d_in[3];
    pa.sg0 = (const float*)d_in[4];  pa.sbb0 = (const float*)d_in[5];
    pa.sm0 = (const float*)d_in[6];  pa.sv0  = (const float*)d_in[7];
    pa.tw0 = (const float*)d_in[8];  pa.tb0  = (const float*)d_in[9];
    pa.tg0 = (const float*)d_in[10]; pa.tbb0 = (const float*)d_in[11];
    pa.tm0 = (const float*)d_in[12]; pa.tv0  = (const float*)d_in[13];
    pa.rw0 = (const float*)d_in[14]; pa.rb0  = (const float*)d_in[15];
    pa.rg0 = (const float*)d_in[16]; pa.rbb0 = (const float*)d_in[17];
    pa.rm0 = (const float*)d_in[18]; pa.rv0  = (const float*)d_in[19];
    pa.sw1 = (const float*)d_in[20]; pa.sb1  = (const float*)d_in[21];
    pa.sg1 = (const float*)d_in[22]; pa.sbb1 = (const float*)d_in[23];
    pa.sm1 = (const float*)d_in[24]; pa.sv1  = (const float*)d_in[25];
    pa.tw1 = (const float*)d_in[26]; pa.tb1  = (const float*)d_in[27];
    pa.tg1 = (const float*)d_in[28]; pa.tbb1 = (const float*)d_in[29];
    pa.tm1 = (const float*)d_in[30]; pa.tv1  = (const float*)d_in[31];
    pa.rw1 = (const float*)d_in[32]; pa.rb1  = (const float*)d_in[33];
    pa.rg1 = (const float*)d_in[34]; pa.rbb1 = (const float*)d_in[35];
    pa.rm1 = (const float*)d_in[36]; pa.rv1  = (const float*)d_in[37];
    pa.projw = (const float*)d_in[38];
    pa.ws = ws;

    prep_kernel<<<dim3(369), dim3(256), 0, stream>>>(pa);

    // chunk batches so y0 fits in ws (y0 is the only large scratch array)
    int chunk = 16;
    while (chunk > 1 && (size_t)Y0_B + Y0_PERB * (size_t)chunk > ws_size) chunk >>= 1;

    for (int cb = 0; cb < 16; cb += chunk) {
        b0_kernel<<<dim3(chunk * 128), dim3(256), 0, stream>>>(x, adj, ws, cb);
        b1_kernel<<<dim3(chunk * 256), dim3(256), 0, stream>>>(adj, projb, ws, (float*)d_out, cb);
    }
}

// Round 2
// 475.465 us; speedup vs baseline: 1.1255x; 1.1255x over previous
//
#include <hip/hip_runtime.h>
#include <hip/hip_bf16.h>
#include <stdint.h>

typedef __attribute__((ext_vector_type(8))) short bf16x8;
typedef __attribute__((ext_vector_type(4))) float f32x4;

#define EPSB 1e-5f

// ---------------- workspace byte offsets ----------------
#define W0TE_B   0u          // [64][192] bf16, k = tap*64 + c
#define W1SB_B   24576u      // [128][64] bf16
#define W1E_B    40960u      // [2][128][192] bf16
#define W1R_B    139264u     // [128][64] bf16
#define PROJW_B  155648u     // [128][128] bf16  (e-major, no transpose)
#define WS0F_B   188416u     // [64][4] f32
#define WR0F_B   189440u     // [64][4] f32
#define BS0F_B   190464u     // [64] f32
#define CB0F_B   190720u     // [64] f32
#define BS1F_B   190976u     // [128] f32
#define CB1F_B   191488u     // [128] f32
#define SPT_B    192000u     // [17][8] float2 {a, k-as-uint-bits}
#define MEANS_B  193536u     // [chunk*2048][128] bf16
#define Y0_PERB  4456448ull  // bytes per batch of y0 (2048*17*64*2)

__device__ __forceinline__ float bf2f(unsigned int u16v) {
    union { unsigned int i; float f; } v; v.i = u16v << 16; return v.f;
}
__device__ __forceinline__ unsigned short f2bf(float f) {
    unsigned int x = __float_as_uint(f);
    x = x + 0x7fffu + ((x >> 16) & 1u);   // RNE
    return (unsigned short)(x >> 16);
}
__device__ __forceinline__ unsigned pk2(float a, float b) {
    union { __hip_bfloat162 h; unsigned u; } v;
    v.h = __float22bfloat162_rn(make_float2(a, b));
    return v.u;
}
__device__ __forceinline__ int div17(int p) { return (p * 241) >> 12; }  // valid p<=255

struct PrepArgs {
    const float *sw0,*sb0,*sg0,*sbb0,*sm0,*sv0;
    const float *tw0,*tb0,*tg0,*tbb0,*tm0,*tv0;
    const float *rw0,*rb0,*rg0,*rbb0,*rm0,*rv0;
    const float *sw1,*sb1,*sg1,*sbb1,*sm1,*sv1;
    const float *tw1,*tb1,*tg1,*tbb1,*tm1,*tv1;
    const float *rw1,*rb1,*rg1,*rbb1,*rm1,*rv1;
    const float *projw;
    const float *adj;
    unsigned char* ws;
};

__global__ void prep_kernel(PrepArgs a) {
    const int g = blockIdx.x * 256 + threadIdx.x;
    unsigned short* W0TE  = (unsigned short*)(a.ws + W0TE_B);
    unsigned short* W1SBp = (unsigned short*)(a.ws + W1SB_B);
    unsigned short* W1Ep  = (unsigned short*)(a.ws + W1E_B);
    unsigned short* W1Rp  = (unsigned short*)(a.ws + W1R_B);
    unsigned short* PROJW = (unsigned short*)(a.ws + PROJW_B);
    float* WS0F = (float*)(a.ws + WS0F_B);
    float* WR0F = (float*)(a.ws + WR0F_B);
    float* BS0F = (float*)(a.ws + BS0F_B);
    float* CB0F = (float*)(a.ws + CB0F_B);
    float* BS1F = (float*)(a.ws + BS1F_B);
    float* CB1F = (float*)(a.ws + CB1F_B);
    float2* SPT = (float2*)(a.ws + SPT_B);

    if (g < 64) {
        int o = g;
        float scs = a.sg0[o] / sqrtf(a.sv0[o] + EPSB);
        BS0F[o] = scs * (a.sb0[o] - a.sm0[o]) + a.sbb0[o];
        for (int c = 0; c < 4; c++) WS0F[o*4+c] = (c < 3) ? scs * a.sw0[o*3+c] : 0.f;
        float tct = a.tg0[o] / sqrtf(a.tv0[o] + EPSB);
        float rcr = a.rg0[o] / sqrtf(a.rv0[o] + EPSB);
        CB0F[o] = tct * (a.tb0[o] - a.tm0[o]) + a.tbb0[o]
                + rcr * (a.rb0[o] - a.rm0[o]) + a.rbb0[o];
        for (int c = 0; c < 4; c++) WR0F[o*4+c] = (c < 3) ? rcr * a.rw0[o*3+c] : 0.f;
    } else if (g < 192) {
        int o = g - 64;
        float scs = a.sg1[o] / sqrtf(a.sv1[o] + EPSB);
        BS1F[o] = scs * (a.sb1[o] - a.sm1[o]) + a.sbb1[o];
        float tct = a.tg1[o] / sqrtf(a.tv1[o] + EPSB);
        float rcr = a.rg1[o] / sqrtf(a.rv1[o] + EPSB);
        CB1F[o] = tct * (a.tb1[o] - a.tm1[o]) + a.tbb1[o]
                + rcr * (a.rb1[o] - a.rm1[o]) + a.rbb1[o];
    } else if (g < 12480) {                   // W0TE: 64*192
        int idx = g - 192;
        int o = idx / 192, k = idx % 192, tap = k >> 6, c = k & 63;
        float tct = a.tg0[o] / sqrtf(a.tv0[o] + EPSB);
        W0TE[o*192 + k] = f2bf(tct * a.tw0[(o*64 + c)*3 + tap]);
    } else if (g < 20672) {                   // W1SB: 128*64
        int idx = g - 12480;
        int o = idx >> 6, c = idx & 63;
        float scs = a.sg1[o] / sqrtf(a.sv1[o] + EPSB);
        W1SBp[o*64 + c] = f2bf(scs * a.sw1[o*64 + c]);
    } else if (g < 69824) {                   // W1E: 2*128*192
        int idx = g - 20672;
        int h = idx / 24576, r = idx % 24576;
        int o = r / 192, k = r % 192, tap = k >> 6, c = (h << 6) + (k & 63);
        float tct = a.tg1[o] / sqrtf(a.tv1[o] + EPSB);
        W1Ep[(h*128 + o)*192 + k] = f2bf(tct * a.tw1[(o*128 + c)*3 + tap]);
    } else if (g < 78016) {                   // W1R: 128*64
        int idx = g - 69824;
        int o = idx >> 6, c = idx & 63;
        float rcr = a.rg1[o] / sqrtf(a.rv1[o] + EPSB);
        W1Rp[o*64 + c] = f2bf(rcr * a.rw1[o*64 + c]);
    } else if (g < 94400) {                   // PROJW: 128*128 direct
        int idx = g - 78016;
        PROJW[idx] = f2bf(a.projw[idx]);
    } else if (g < 94417) {                   // sparse adj columns
        int j = g - 94400;
        int cnt = 0;
        for (int k = 0; k < 17; k++) {
            float v = a.adj[k*17 + j];
            if (v != 0.0f && cnt < 8) {
                SPT[j*8 + cnt] = make_float2(v, __uint_as_float((unsigned)k));
                cnt++;
            }
        }
        for (; cnt < 8; cnt++) SPT[j*8 + cnt] = make_float2(0.f, __uint_as_float(0u));
    }
}

// ---------------- block 0: 3 -> 64, T-tile 8 ----------------
__launch_bounds__(256, 3)
__global__ void b0_kernel(const float* __restrict__ x,
                          const unsigned char* __restrict__ ws,
                          unsigned short* __restrict__ Y0, int b0base) {
    __shared__ float xt[510];                 // [3][170]
    __shared__ float xg[510];
    __shared__ float2 spt[136];
    __shared__ float Ws0s[256], Wr0s[256], bs0s[64], cb0s[64];
    __shared__ __align__(16) unsigned short s0[170*72];
    __shared__ __align__(16) unsigned short yst[136*72];

    const int tid = threadIdx.x;
    const int b_loc = blockIdx.x >> 8;
    const int b = b0base + b_loc;
    const int t0 = (blockIdx.x & 255) << 3;
    const int Pb = (t0 - 1) * 17;

    const int w = tid >> 6, l = tid & 63, lr = l & 15, lg = l >> 4;
    const int n = w*16 + lr;

    // weights to regs (issued first, used much later)
    const unsigned short* W0TE = (const unsigned short*)(ws + W0TE_B);
    bf16x8 bfr[6];
    #pragma unroll
    for (int ks = 0; ks < 6; ks++)
        bfr[ks] = *(const bf16x8*)&W0TE[n*192 + ks*32 + lg*8];

    if (tid < 136) {
        float2 raw = ((const float2*)(ws + SPT_B))[tid];
        spt[tid] = make_float2(raw.x, __uint_as_float(__float_as_uint(raw.y) * 4u));
    }
    Ws0s[tid] = ((const float*)(ws + WS0F_B))[tid];
    Wr0s[tid] = ((const float*)(ws + WR0F_B))[tid];
    if (tid < 64) {
        bs0s[tid] = ((const float*)(ws + BS0F_B))[tid];
        cb0s[tid] = ((const float*)(ws + CB0F_B))[tid];
    }
    #pragma unroll
    for (int it = 0; it < 2; it++) {          // x -> LDS (contiguous in pos)
        int idx = tid + it*256;
        if (idx < 510) {
            int c = idx / 170, r = idx - c*170;
            int P = Pb + r;
            float v = 0.f;
            if (P >= 0 && P < 34816) v = x[(size_t)(b*3 + c)*34816 + P];
            xt[idx] = v;
        }
    }
    __syncthreads();
    #pragma unroll
    for (int it = 0; it < 2; it++) {          // sparse graph conv
        int idx = tid + it*256;
        if (idx < 510) {
            int c = idx / 170, r = idx - c*170;
            int j = r - 17*div17(r);
            const char* rowb = (const char*)&xt[c*170 + (r - j)];
            float acc = 0.f;
            #pragma unroll
            for (int i = 0; i < 8; i++) {
                float2 e = spt[j*8 + i];
                acc += e.x * *(const float*)(rowb + __float_as_uint(e.y));
            }
            xg[idx] = acc;
        }
    }
    __syncthreads();
    #pragma unroll
    for (int it = 0; it < 11; it++) {         // s0 = relu(conv1x1(xg)), zero OOB rows
        int idx = tid + it*256;
        if (idx < 2720) {
            int r = idx >> 4, cg = idx & 15, o0 = cg*4;
            int P = Pb + r;
            uint2 pkv = make_uint2(0u, 0u);
            if (P >= 0 && P < 34816) {
                float a0 = xg[r], a1 = xg[170 + r], a2 = xg[340 + r];
                float v0 = fmaxf(bs0s[o0]   + Ws0s[(o0  )*4]*a0 + Ws0s[(o0  )*4+1]*a1 + Ws0s[(o0  )*4+2]*a2, 0.f);
                float v1 = fmaxf(bs0s[o0+1] + Ws0s[(o0+1)*4]*a0 + Ws0s[(o0+1)*4+1]*a1 + Ws0s[(o0+1)*4+2]*a2, 0.f);
                float v2 = fmaxf(bs0s[o0+2] + Ws0s[(o0+2)*4]*a0 + Ws0s[(o0+2)*4+1]*a1 + Ws0s[(o0+2)*4+2]*a2, 0.f);
                float v3 = fmaxf(bs0s[o0+3] + Ws0s[(o0+3)*4]*a0 + Ws0s[(o0+3)*4+1]*a1 + Ws0s[(o0+3)*4+2]*a2, 0.f);
                pkv.x = pk2(v0, v1); pkv.y = pk2(v2, v3);
            }
            *(uint2*)&s0[r*72 + o0] = pkv;
        }
    }
    __syncthreads();
    {   // tconv GEMM + residual -> yst
        const float wr0 = Wr0s[n*4], wr1 = Wr0s[n*4+1], wr2 = Wr0s[n*4+2];
        const float cbn = cb0s[n];
        for (int mb = 0; mb < 9; mb++) {
            const int ra = mb*16 + lr;
            f32x4 acc = {0.f, 0.f, 0.f, 0.f};
            #pragma unroll
            for (int ks = 0; ks < 6; ks++) {
                int row = ra + (ks >> 1)*17; if (row > 169) row = 169;
                const int c0 = ((ks & 1) << 5) + lg*8;
                acc = __builtin_amdgcn_mfma_f32_16x16x32_bf16(
                    *(const bf16x8*)&s0[row*72 + c0], bfr[ks], acc, 0, 0, 0);
            }
            const int mbase = mb*16 + lg*4;
            #pragma unroll
            for (int i = 0; i < 4; i++) {
                const int m = mbase + i;
                if (m < 136) {
                    float v = acc[i] + cbn + wr0*xt[m+17] + wr1*xt[170+m+17] + wr2*xt[340+m+17];
                    yst[m*72 + n] = f2bf(fmaxf(v, 0.f));
                }
            }
        }
    }
    __syncthreads();
    #pragma unroll
    for (int it = 0; it < 5; it++) {          // vectorized y0 store (contiguous in m)
        int idx = tid + it*256;
        if (idx < 1088) {
            int m = idx >> 3, seg = idx & 7;
            uint4 v = *(const uint4*)&yst[m*72 + seg*8];
            *(uint4*)&Y0[((size_t)b_loc*34816 + t0*17 + m)*64 + seg*8] = v;
        }
    }
}

// ---------------- block 1: 64 -> 128 + mean, persistent over 8 t-tiles ----------------
__launch_bounds__(512, 4)
__global__ void b1_kernel(const unsigned char* __restrict__ ws,
                          const unsigned short* __restrict__ Y0,
                          unsigned short* __restrict__ MEANS) {
    __shared__ __align__(16) unsigned short buf[24480];   // bufA [170][72] | ygs [170][72]; y1 [136][132] overlay
    __shared__ float2 spt[136];
    __shared__ float cb1s[128], bs1s[128];

    unsigned short* bufA = buf;
    unsigned short* ygs  = buf + 12240;
    unsigned short* y1   = buf;

    const int tid = threadIdx.x;
    const int b_loc = blockIdx.x >> 5;
    const int ck = blockIdx.x & 31;

    const unsigned short* W1SBp = (const unsigned short*)(ws + W1SB_B);
    const unsigned short* W1Ep  = (const unsigned short*)(ws + W1E_B);
    const unsigned short* W1Rp  = (const unsigned short*)(ws + W1R_B);

    const int w = tid >> 6, l = tid & 63, lr = l & 15, lg = l >> 4;
    const int n = w*16 + lr;                  // tconv/resid column (0..127)
    const int sNt = w & 3, sMh = w >> 2;      // s1 assignment
    const int nloc_s = sNt*16 + lr;

    if (tid < 136) {
        float2 raw = ((const float2*)(ws + SPT_B))[tid];
        spt[tid] = make_float2(raw.x, __uint_as_float(__float_as_uint(raw.y) * 144u));
    }
    if (tid < 128) {
        cb1s[tid] = ((const float*)(ws + CB1F_B))[tid];
        bs1s[tid] = ((const float*)(ws + BS1F_B))[tid];
    }
    // persistent weight fragments
    bf16x8 rb0 = *(const bf16x8*)&W1Rp[n*64 + lg*8];
    bf16x8 rb1 = *(const bf16x8*)&W1Rp[n*64 + 32 + lg*8];
    bf16x8 sb00 = *(const bf16x8*)&W1SBp[(nloc_s     )*64 + lg*8];
    bf16x8 sb01 = *(const bf16x8*)&W1SBp[(nloc_s     )*64 + 32 + lg*8];
    bf16x8 sb10 = *(const bf16x8*)&W1SBp[(64 + nloc_s)*64 + lg*8];
    bf16x8 sb11 = *(const bf16x8*)&W1SBp[(64 + nloc_s)*64 + 32 + lg*8];

    uint4 pf[3];
    // initial prefetch (tile 0)
    {
        const int t0n = ck << 6;
        #pragma unroll
        for (int s = 0; s < 3; s++) {
            int idx = tid + s*512;
            uint4 v = make_uint4(0u,0u,0u,0u);
            if (idx < 1360) {
                int p = idx >> 3, seg = idx & 7;
                int P = (t0n - 1)*17 + p;
                if (P >= 0 && P < 34816)
                    v = *(const uint4*)&Y0[((size_t)b_loc*34816 + P)*64 + seg*8];
            }
            pf[s] = v;
        }
    }

    for (int tt = 0; tt < 8; tt++) {
        const int t0 = (ck << 6) + (tt << 3);
        const int Pb = (t0 - 1) * 17;

        // A: commit prefetched y0 tile
        #pragma unroll
        for (int s = 0; s < 3; s++) {
            int idx = tid + s*512;
            if (idx < 1360) {
                int p = idx >> 3, seg = idx & 7;
                *(uint4*)&bufA[p*72 + seg*8] = pf[s];
            }
        }
        __syncthreads();

        // B: prefetch next tile + W1E h0 frags + residual GEMM + sparse graph conv
        if (tt < 7) {
            const int t0n = t0 + 8;
            #pragma unroll
            for (int s = 0; s < 3; s++) {
                int idx = tid + s*512;
                uint4 v = make_uint4(0u,0u,0u,0u);
                if (idx < 1360) {
                    int p = idx >> 3, seg = idx & 7;
                    int P = (t0n - 1)*17 + p;
                    if (P >= 0 && P < 34816)
                        v = *(const uint4*)&Y0[((size_t)b_loc*34816 + P)*64 + seg*8];
                }
                pf[s] = v;
            }
        }
        bf16x8 bfh[6];
        #pragma unroll
        for (int ks = 0; ks < 6; ks++)
            bfh[ks] = *(const bf16x8*)&W1Ep[n*192 + ks*32 + lg*8];   // h=0

        f32x4 tacc[9];
        #pragma unroll
        for (int mb = 0; mb < 9; mb++) {
            const int row = mb*16 + lr + 17;
            f32x4 acc = {0.f, 0.f, 0.f, 0.f};
            acc = __builtin_amdgcn_mfma_f32_16x16x32_bf16(*(const bf16x8*)&bufA[row*72 + lg*8],      rb0, acc, 0, 0, 0);
            acc = __builtin_amdgcn_mfma_f32_16x16x32_bf16(*(const bf16x8*)&bufA[row*72 + 32 + lg*8], rb1, acc, 0, 0, 0);
            tacc[mb] = acc;
        }
        #pragma unroll
        for (int q = 0; q < 6; q++) {         // graph conv -> ygs
            int idx = tid + q*512;
            if (idx < 2720) {
                int p = idx >> 4, cg = idx & 15;
                int j = p - 17*div17(p);
                const char* rowb = (const char*)bufA + (p - j)*144 + cg*8;
                float a0=0.f, a1=0.f, a2=0.f, a3=0.f;
                #pragma unroll
                for (int i = 0; i < 8; i++) {
                    float2 e = spt[j*8 + i];
                    uint2 u = *(const uint2*)(rowb + __float_as_uint(e.y));
                    a0 += e.x * __uint_as_float(u.x << 16);
                    a1 += e.x * __uint_as_float(u.x & 0xffff0000u);
                    a2 += e.x * __uint_as_float(u.y << 16);
                    a3 += e.x * __uint_as_float(u.y & 0xffff0000u);
                }
                uint2 o; o.x = pk2(a0, a1); o.y = pk2(a2, a3);
                *(uint2*)&ygs[p*72 + cg*4] = o;
            }
        }
        __syncthreads();

        // C: s1 h0 -> bufA
        {
            const int mbE = sMh ? 11 : 6;
            for (int mb = sMh ? 6 : 0; mb < mbE; mb++) {
                int ra = mb*16 + lr; if (ra > 169) ra = 169;
                f32x4 sa = {0.f, 0.f, 0.f, 0.f};
                sa = __builtin_amdgcn_mfma_f32_16x16x32_bf16(*(const bf16x8*)&ygs[ra*72 + lg*8],      sb00, sa, 0, 0, 0);
                sa = __builtin_amdgcn_mfma_f32_16x16x32_bf16(*(const bf16x8*)&ygs[ra*72 + 32 + lg*8], sb01, sa, 0, 0, 0);
                const int mbase = mb*16 + lg*4;
                #pragma unroll
                for (int i = 0; i < 4; i++) {
                    int m = mbase + i;
                    if (m < 170) {
                        int P = Pb + m;
                        float v = (P >= 0 && P < 34816) ? fmaxf(sa[i] + bs1s[nloc_s], 0.f) : 0.f;
                        bufA[m*72 + nloc_s] = f2bf(v);
                    }
                }
            }
        }
        __syncthreads();

        // D: tconv h0
        #pragma unroll
        for (int mb = 0; mb < 9; mb++) {
            const int ma = mb*16 + lr;
            f32x4 acc = tacc[mb];
            #pragma unroll
            for (int ks = 0; ks < 6; ks++) {
                int row = ma + (ks >> 1)*17; if (row > 169) row = 169;
                const int c0 = ((ks & 1) << 5) + lg*8;
                acc = __builtin_amdgcn_mfma_f32_16x16x32_bf16(
                    *(const bf16x8*)&bufA[row*72 + c0], bfh[ks], acc, 0, 0, 0);
            }
            tacc[mb] = acc;
        }
        __syncthreads();

        // E: W1E h1 frags + s1 h1 -> bufA
        #pragma unroll
        for (int ks = 0; ks < 6; ks++)
            bfh[ks] = *(const bf16x8*)&W1Ep[(128 + n)*192 + ks*32 + lg*8];
        {
            const int mbE = sMh ? 11 : 6;
            for (int mb = sMh ? 6 : 0; mb < mbE; mb++) {
                int ra = mb*16 + lr; if (ra > 169) ra = 169;
                f32x4 sa = {0.f, 0.f, 0.f, 0.f};
                sa = __builtin_amdgcn_mfma_f32_16x16x32_bf16(*(const bf16x8*)&ygs[ra*72 + lg*8],      sb10, sa, 0, 0, 0);
                sa = __builtin_amdgcn_mfma_f32_16x16x32_bf16(*(const bf16x8*)&ygs[ra*72 + 32 + lg*8], sb11, sa, 0, 0, 0);
                const int mbase = mb*16 + lg*4;
                #pragma unroll
                for (int i = 0; i < 4; i++) {
                    int m = mbase + i;
                    if (m < 170) {
                        int P = Pb + m;
                        float v = (P >= 0 && P < 34816) ? fmaxf(sa[i] + bs1s[64 + nloc_s], 0.f) : 0.f;
                        bufA[m*72 + nloc_s] = f2bf(v);
                    }
                }
            }
        }
        __syncthreads();

        // F1: tconv h1
        #pragma unroll
        for (int mb = 0; mb < 9; mb++) {
            const int ma = mb*16 + lr;
            f32x4 acc = tacc[mb];
            #pragma unroll
            for (int ks = 0; ks < 6; ks++) {
                int row = ma + (ks >> 1)*17; if (row > 169) row = 169;
                const int c0 = ((ks & 1) << 5) + lg*8;
                acc = __builtin_amdgcn_mfma_f32_16x16x32_bf16(
                    *(const bf16x8*)&bufA[row*72 + c0], bfh[ks], acc, 0, 0, 0);
            }
            tacc[mb] = acc;
        }
        __syncthreads();

        // F2: y1 = relu(tconv + resid + bias) -> overlay buffer [136][132]
        #pragma unroll
        for (int mb = 0; mb < 9; mb++) {
            const int mbase = mb*16 + lg*4;
            #pragma unroll
            for (int i = 0; i < 4; i++) {
                int m = mbase + i;
                if (m < 136)
                    y1[m*132 + n] = f2bf(fmaxf(tacc[mb][i] + cb1s[n], 0.f));
            }
        }
        __syncthreads();

        // G: mean over J -> MEANS (bf16)
        {
            const int t = tid >> 6, n2 = (tid & 63) * 2;
            float s0v = 0.f, s1v = 0.f;
            #pragma unroll
            for (int jj = 0; jj < 17; jj++) {
                unsigned u = *(const unsigned*)&y1[(t*17 + jj)*132 + n2];
                s0v += __uint_as_float(u << 16);
                s1v += __uint_as_float(u & 0xffff0000u);
            }
            const float sc = 1.f / 17.f;
            *(unsigned*)&MEANS[((size_t)(b_loc*2048 + t0 + t))*128 + n2] = pk2(s0v*sc, s1v*sc);
        }
        __syncthreads();
    }
}

// ---------------- projection: [chunk*2048,128] x [128,128] ----------------
__launch_bounds__(256, 3)
__global__ void proj_kernel(const unsigned short* __restrict__ MEANS,
                            const unsigned char* __restrict__ ws,
                            const float* __restrict__ projb,
                            float* __restrict__ outp, int bt_base) {
    __shared__ __align__(16) unsigned short As[128*136];
    __shared__ float pbs[128];

    const int tid = threadIdx.x;
    const int m0 = blockIdx.x * 128;
    const int w = tid >> 6, l = tid & 63, lr = l & 15, lg = l >> 4;
    const unsigned short* PROJW = (const unsigned short*)(ws + PROJW_B);

    if (tid < 128) pbs[tid] = projb[tid];
    #pragma unroll
    for (int it = 0; it < 8; it++) {
        int idx = tid + it*256;
        int m = idx >> 4, seg = idx & 15;
        *(uint4*)&As[m*136 + seg*8] = *(const uint4*)&MEANS[(size_t)(m0 + m)*128 + seg*8];
    }
    __syncthreads();

    f32x4 acc[8][2];
    #pragma unroll
    for (int et = 0; et < 8; et++) {
        const int e = et*16 + lr;
        bf16x8 bf[4];
        #pragma unroll
        for (int kf = 0; kf < 4; kf++)
            bf[kf] = *(const bf16x8*)&PROJW[e*128 + kf*32 + lg*8];
        #pragma unroll
        for (int m2 = 0; m2 < 2; m2++) {
            const int ra = (w*2 + m2)*16 + lr;
            f32x4 a = {0.f, 0.f, 0.f, 0.f};
            #pragma unroll
            for (int kf = 0; kf < 4; kf++)
                a = __builtin_amdgcn_mfma_f32_16x16x32_bf16(
                    *(const bf16x8*)&As[ra*136 + kf*32 + lg*8], bf[kf], a, 0, 0, 0);
            acc[et][m2] = a;
        }
    }
    #pragma unroll
    for (int et = 0; et < 8; et++) {
        const int e = et*16 + lr;
        const float pb = pbs[e];
        #pragma unroll
        for (int m2 = 0; m2 < 2; m2++) {
            const int mbase = (w*2 + m2)*16 + lg*4;
            #pragma unroll
            for (int i = 0; i < 4; i++) {
                const int m = mbase + i;
                outp[(size_t)(bt_base + m0 + m)*128 + e] = acc[et][m2][i] + pb;
            }
        }
    }
}

extern "C" void kernel_launch(void* const* d_in, const int* in_sizes, int n_in,
                              void* d_out, int out_size, void* d_ws, size_t ws_size,
                              hipStream_t stream) {
    const float* x     = (const float*)d_in[0];
    const float* adj   = (const float*)d_in[1];
    const float* projb = (const float*)d_in[39];
    unsigned char* ws  = (unsigned char*)d_ws;

    PrepArgs pa;
    pa.sw0 = (const float*)d_in[2];  pa.sb0  = (const float*)d_in[3];
    pa.sg0 = (const float*)d_in[4];  pa.sbb0 = (const float*)d_in[5];
    pa.sm0 = (const float*)d_in[6];  pa.sv0  = (const float*)d_in[7];
    pa.tw0 = (const float*)d_in[8];  pa.tb0  = (const float*)d_in[9];
    pa.tg0 = (const float*)d_in[10]; pa.tbb0 = (const float*)d_in[11];
    pa.tm0 = (const float*)d_in[12]; pa.tv0  = (const float*)d_in[13];
    pa.rw0 = (const float*)d_in[14]; pa.rb0  = (const float*)d_in[15];
    pa.rg0 = (const float*)d_in[16]; pa.rbb0 = (const float*)d_in[17];
    pa.rm0 = (const float*)d_in[18]; pa.rv0  = (const float*)d_in[19];
    pa.sw1 = (const float*)d_in[20]; pa.sb1  = (const float*)d_in[21];
    pa.sg1 = (const float*)d_in[22]; pa.sbb1 = (const float*)d_in[23];
    pa.sm1 = (const float*)d_in[24]; pa.sv1  = (const float*)d_in[25];
    pa.tw1 = (const float*)d_in[26]; pa.tb1  = (const float*)d_in[27];
    pa.tg1 = (const float*)d_in[28]; pa.tbb1 = (const float*)d_in[29];
    pa.tm1 = (const float*)d_in[30]; pa.tv1  = (const float*)d_in[31];
    pa.rw1 = (const float*)d_in[32]; pa.rb1  = (const float*)d_in[33];
    pa.rg1 = (const float*)d_in[34]; pa.rbb1 = (const float*)d_in[35];
    pa.rm1 = (const float*)d_in[36]; pa.rv1  = (const float*)d_in[37];
    pa.projw = (const float*)d_in[38];
    pa.adj = adj;
    pa.ws = ws;

    prep_kernel<<<dim3(369), dim3(256), 0, stream>>>(pa);

    int chunk = 16;
    while (chunk > 1 &&
           (size_t)MEANS_B + (size_t)chunk * (524288ull + Y0_PERB) > ws_size)
        chunk >>= 1;

    unsigned short* MEANSp = (unsigned short*)(ws + MEANS_B);
    unsigned short* Y0p    = (unsigned short*)(ws + MEANS_B + (size_t)chunk * 524288ull);

    for (int cb = 0; cb < 16; cb += chunk) {
        b0_kernel<<<dim3(chunk * 256), dim3(256), 0, stream>>>(x, ws, Y0p, cb);
        b1_kernel<<<dim3(chunk * 32), dim3(512), 0, stream>>>(ws, Y0p, MEANSp);
        proj_kernel<<<dim3(chunk * 16), dim3(256), 0, stream>>>(MEANSp, ws, projb, (float*)d_out, cb * 2048);
    }
}

// Round 3
// 395.391 us; speedup vs baseline: 1.3534x; 1.2025x over previous
//
#include <hip/hip_runtime.h>
#include <hip/hip_bf16.h>
#include <stdint.h>

typedef __attribute__((ext_vector_type(8))) short bf16x8;
typedef __attribute__((ext_vector_type(4))) float f32x4;

#define EPSB 1e-5f

// ---------------- workspace byte offsets ----------------
#define W0TE_B   0u          // [64][192] bf16, k = tap*64 + c
#define W1SB_B   24576u      // [128][64] bf16
#define W1E_B    40960u      // [2][128][192] bf16
#define W1R_B    139264u     // [128][64] bf16
#define PROJW_B  155648u     // [128][128] bf16  (e-major, no transpose)
#define WS0F_B   188416u     // [64][4] f32
#define WR0F_B   189440u     // [64][4] f32
#define BS0F_B   190464u     // [64] f32
#define CB0F_B   190720u     // [64] f32
#define BS1F_B   190976u     // [128] f32
#define CB1F_B   191488u     // [128] f32
#define SPT_B    192000u     // [17][8] float2 {a, k-as-uint-bits}
#define MEANS_B  193536u     // [chunk*2048][128] bf16
#define Y0_PERB  4456448ull  // bytes per batch of y0 (2048*17*64*2)

__device__ __forceinline__ float bf2f(unsigned int u16v) {
    union { unsigned int i; float f; } v; v.i = u16v << 16; return v.f;
}
__device__ __forceinline__ unsigned short f2bf(float f) {
    unsigned int x = __float_as_uint(f);
    x = x + 0x7fffu + ((x >> 16) & 1u);   // RNE
    return (unsigned short)(x >> 16);
}
__device__ __forceinline__ unsigned pk2(float a, float b) {
    union { __hip_bfloat162 h; unsigned u; } v;
    v.h = __float22bfloat162_rn(make_float2(a, b));
    return v.u;
}
__device__ __forceinline__ int div17(int p) { return (p * 241) >> 12; }  // valid p<=255

struct PrepArgs {
    const float *sw0,*sb0,*sg0,*sbb0,*sm0,*sv0;
    const float *tw0,*tb0,*tg0,*tbb0,*tm0,*tv0;
    const float *rw0,*rb0,*rg0,*rbb0,*rm0,*rv0;
    const float *sw1,*sb1,*sg1,*sbb1,*sm1,*sv1;
    const float *tw1,*tb1,*tg1,*tbb1,*tm1,*tv1;
    const float *rw1,*rb1,*rg1,*rbb1,*rm1,*rv1;
    const float *projw;
    const float *adj;
    unsigned char* ws;
};

__global__ void prep_kernel(PrepArgs a) {
    const int g = blockIdx.x * 256 + threadIdx.x;
    unsigned short* W0TE  = (unsigned short*)(a.ws + W0TE_B);
    unsigned short* W1SBp = (unsigned short*)(a.ws + W1SB_B);
    unsigned short* W1Ep  = (unsigned short*)(a.ws + W1E_B);
    unsigned short* W1Rp  = (unsigned short*)(a.ws + W1R_B);
    unsigned short* PROJW = (unsigned short*)(a.ws + PROJW_B);
    float* WS0F = (float*)(a.ws + WS0F_B);
    float* WR0F = (float*)(a.ws + WR0F_B);
    float* BS0F = (float*)(a.ws + BS0F_B);
    float* CB0F = (float*)(a.ws + CB0F_B);
    float* BS1F = (float*)(a.ws + BS1F_B);
    float* CB1F = (float*)(a.ws + CB1F_B);
    float2* SPT = (float2*)(a.ws + SPT_B);

    if (g < 64) {
        int o = g;
        float scs = a.sg0[o] / sqrtf(a.sv0[o] + EPSB);
        BS0F[o] = scs * (a.sb0[o] - a.sm0[o]) + a.sbb0[o];
        for (int c = 0; c < 4; c++) WS0F[o*4+c] = (c < 3) ? scs * a.sw0[o*3+c] : 0.f;
        float tct = a.tg0[o] / sqrtf(a.tv0[o] + EPSB);
        float rcr = a.rg0[o] / sqrtf(a.rv0[o] + EPSB);
        CB0F[o] = tct * (a.tb0[o] - a.tm0[o]) + a.tbb0[o]
                + rcr * (a.rb0[o] - a.rm0[o]) + a.rbb0[o];
        for (int c = 0; c < 4; c++) WR0F[o*4+c] = (c < 3) ? rcr * a.rw0[o*3+c] : 0.f;
    } else if (g < 192) {
        int o = g - 64;
        float scs = a.sg1[o] / sqrtf(a.sv1[o] + EPSB);
        BS1F[o] = scs * (a.sb1[o] - a.sm1[o]) + a.sbb1[o];
        float tct = a.tg1[o] / sqrtf(a.tv1[o] + EPSB);
        float rcr = a.rg1[o] / sqrtf(a.rv1[o] + EPSB);
        CB1F[o] = tct * (a.tb1[o] - a.tm1[o]) + a.tbb1[o]
                + rcr * (a.rb1[o] - a.rm1[o]) + a.rbb1[o];
    } else if (g < 12480) {                   // W0TE: 64*192
        int idx = g - 192;
        int o = idx / 192, k = idx % 192, tap = k >> 6, c = k & 63;
        float tct = a.tg0[o] / sqrtf(a.tv0[o] + EPSB);
        W0TE[o*192 + k] = f2bf(tct * a.tw0[(o*64 + c)*3 + tap]);
    } else if (g < 20672) {                   // W1SB: 128*64
        int idx = g - 12480;
        int o = idx >> 6, c = idx & 63;
        float scs = a.sg1[o] / sqrtf(a.sv1[o] + EPSB);
        W1SBp[o*64 + c] = f2bf(scs * a.sw1[o*64 + c]);
    } else if (g < 69824) {                   // W1E: 2*128*192
        int idx = g - 20672;
        int h = idx / 24576, r = idx % 24576;
        int o = r / 192, k = r % 192, tap = k >> 6, c = (h << 6) + (k & 63);
        float tct = a.tg1[o] / sqrtf(a.tv1[o] + EPSB);
        W1Ep[(h*128 + o)*192 + k] = f2bf(tct * a.tw1[(o*128 + c)*3 + tap]);
    } else if (g < 78016) {                   // W1R: 128*64
        int idx = g - 69824;
        int o = idx >> 6, c = idx & 63;
        float rcr = a.rg1[o] / sqrtf(a.rv1[o] + EPSB);
        W1Rp[o*64 + c] = f2bf(rcr * a.rw1[o*64 + c]);
    } else if (g < 94400) {                   // PROJW: 128*128 direct
        int idx = g - 78016;
        PROJW[idx] = f2bf(a.projw[idx]);
    } else if (g < 94417) {                   // sparse adj columns
        int j = g - 94400;
        int cnt = 0;
        for (int k = 0; k < 17; k++) {
            float v = a.adj[k*17 + j];
            if (v != 0.0f && cnt < 8) {
                SPT[j*8 + cnt] = make_float2(v, __uint_as_float((unsigned)k));
                cnt++;
            }
        }
        for (; cnt < 8; cnt++) SPT[j*8 + cnt] = make_float2(0.f, __uint_as_float(0u));
    }
}

// ---------------- block 0: 3 -> 64, T-tile 8 ----------------
__launch_bounds__(256, 3)
__global__ void b0_kernel(const float* __restrict__ x,
                          const unsigned char* __restrict__ ws,
                          unsigned short* __restrict__ Y0, int b0base) {
    __shared__ float xt[510];                 // [3][170]
    __shared__ float xg[510];
    __shared__ float2 spt[136];
    __shared__ float Ws0s[256], Wr0s[256], bs0s[64], cb0s[64];
    __shared__ __align__(16) unsigned short s0[170*72];
    __shared__ __align__(16) unsigned short yst[136*72];

    const int tid = threadIdx.x;
    const int b_loc = blockIdx.x >> 8;
    const int b = b0base + b_loc;
    const int t0 = (blockIdx.x & 255) << 3;
    const int Pb = (t0 - 1) * 17;

    const int w = tid >> 6, l = tid & 63, lr = l & 15, lg = l >> 4;
    const int n = w*16 + lr;

    // weights to regs (issued first, used much later)
    const unsigned short* W0TE = (const unsigned short*)(ws + W0TE_B);
    bf16x8 bfr[6];
    #pragma unroll
    for (int ks = 0; ks < 6; ks++)
        bfr[ks] = *(const bf16x8*)&W0TE[n*192 + ks*32 + lg*8];

    if (tid < 136) {
        float2 raw = ((const float2*)(ws + SPT_B))[tid];
        spt[tid] = make_float2(raw.x, __uint_as_float(__float_as_uint(raw.y) * 4u));
    }
    Ws0s[tid] = ((const float*)(ws + WS0F_B))[tid];
    Wr0s[tid] = ((const float*)(ws + WR0F_B))[tid];
    if (tid < 64) {
        bs0s[tid] = ((const float*)(ws + BS0F_B))[tid];
        cb0s[tid] = ((const float*)(ws + CB0F_B))[tid];
    }
    #pragma unroll
    for (int it = 0; it < 2; it++) {          // x -> LDS (contiguous in pos)
        int idx = tid + it*256;
        if (idx < 510) {
            int c = idx / 170, r = idx - c*170;
            int P = Pb + r;
            float v = 0.f;
            if (P >= 0 && P < 34816) v = x[(size_t)(b*3 + c)*34816 + P];
            xt[idx] = v;
        }
    }
    __syncthreads();
    #pragma unroll
    for (int it = 0; it < 2; it++) {          // sparse graph conv
        int idx = tid + it*256;
        if (idx < 510) {
            int c = idx / 170, r = idx - c*170;
            int j = r - 17*div17(r);
            const char* rowb = (const char*)&xt[c*170 + (r - j)];
            float acc = 0.f;
            #pragma unroll
            for (int i = 0; i < 8; i++) {
                float2 e = spt[j*8 + i];
                acc += e.x * *(const float*)(rowb + __float_as_uint(e.y));
            }
            xg[idx] = acc;
        }
    }
    __syncthreads();
    #pragma unroll
    for (int it = 0; it < 11; it++) {         // s0 = relu(conv1x1(xg)), zero OOB rows
        int idx = tid + it*256;
        if (idx < 2720) {
            int r = idx >> 4, cg = idx & 15, o0 = cg*4;
            int P = Pb + r;
            uint2 pkv = make_uint2(0u, 0u);
            if (P >= 0 && P < 34816) {
                float a0 = xg[r], a1 = xg[170 + r], a2 = xg[340 + r];
                float v0 = fmaxf(bs0s[o0]   + Ws0s[(o0  )*4]*a0 + Ws0s[(o0  )*4+1]*a1 + Ws0s[(o0  )*4+2]*a2, 0.f);
                float v1 = fmaxf(bs0s[o0+1] + Ws0s[(o0+1)*4]*a0 + Ws0s[(o0+1)*4+1]*a1 + Ws0s[(o0+1)*4+2]*a2, 0.f);
                float v2 = fmaxf(bs0s[o0+2] + Ws0s[(o0+2)*4]*a0 + Ws0s[(o0+2)*4+1]*a1 + Ws0s[(o0+2)*4+2]*a2, 0.f);
                float v3 = fmaxf(bs0s[o0+3] + Ws0s[(o0+3)*4]*a0 + Ws0s[(o0+3)*4+1]*a1 + Ws0s[(o0+3)*4+2]*a2, 0.f);
                pkv.x = pk2(v0, v1); pkv.y = pk2(v2, v3);
            }
            *(uint2*)&s0[r*72 + o0] = pkv;
        }
    }
    __syncthreads();
    {   // tconv GEMM + residual -> yst
        const float wr0 = Wr0s[n*4], wr1 = Wr0s[n*4+1], wr2 = Wr0s[n*4+2];
        const float cbn = cb0s[n];
        for (int mb = 0; mb < 9; mb++) {
            const int ra = mb*16 + lr;
            f32x4 acc = {0.f, 0.f, 0.f, 0.f};
            #pragma unroll
            for (int ks = 0; ks < 6; ks++) {
                int row = ra + (ks >> 1)*17; if (row > 169) row = 169;
                const int c0 = ((ks & 1) << 5) + lg*8;
                acc = __builtin_amdgcn_mfma_f32_16x16x32_bf16(
                    *(const bf16x8*)&s0[row*72 + c0], bfr[ks], acc, 0, 0, 0);
            }
            const int mbase = mb*16 + lg*4;
            #pragma unroll
            for (int i = 0; i < 4; i++) {
                const int m = mbase + i;
                if (m < 136) {
                    float v = acc[i] + cbn + wr0*xt[m+17] + wr1*xt[170+m+17] + wr2*xt[340+m+17];
                    yst[m*72 + n] = f2bf(fmaxf(v, 0.f));
                }
            }
        }
    }
    __syncthreads();
    #pragma unroll
    for (int it = 0; it < 5; it++) {          // vectorized y0 store (contiguous in m)
        int idx = tid + it*256;
        if (idx < 1088) {
            int m = idx >> 3, seg = idx & 7;
            uint4 v = *(const uint4*)&yst[m*72 + seg*8];
            *(uint4*)&Y0[((size_t)b_loc*34816 + t0*17 + m)*64 + seg*8] = v;
        }
    }
}

// ---------------- block 1: 64 -> 128 + mean, persistent over 8 t-tiles ----------------
// __launch_bounds__ 2nd arg acts as min-BLOCKS/CU here (R2 evidence: (512,4) -> VGPR=64).
// (512,2): 2 blocks/CU, VGPR cap 128, no spill.
__launch_bounds__(512, 2)
__global__ void b1_kernel(const unsigned char* __restrict__ ws,
                          const unsigned short* __restrict__ Y0,
                          unsigned short* __restrict__ MEANS) {
    __shared__ __align__(16) unsigned short buf[24480];   // bufA [170][72] | ygs [170][72]; y1 [136][132] overlay
    __shared__ float2 spt[136];
    __shared__ float cb1s[128], bs1s[128];

    unsigned short* bufA = buf;
    unsigned short* ygs  = buf + 12240;
    unsigned short* y1   = buf;

    const int tid = threadIdx.x;
    const int b_loc = blockIdx.x >> 5;
    const int ck = blockIdx.x & 31;

    const unsigned short* W1SBp = (const unsigned short*)(ws + W1SB_B);
    const unsigned short* W1Ep  = (const unsigned short*)(ws + W1E_B);
    const unsigned short* W1Rp  = (const unsigned short*)(ws + W1R_B);

    const int w = tid >> 6, l = tid & 63, lr = l & 15, lg = l >> 4;
    const int n = w*16 + lr;                  // tconv/resid column (0..127)
    const int sNt = w & 3, sMh = w >> 2;      // s1 assignment
    const int nloc_s = sNt*16 + lr;

    if (tid < 136) {
        float2 raw = ((const float2*)(ws + SPT_B))[tid];
        spt[tid] = make_float2(raw.x, __uint_as_float(__float_as_uint(raw.y) * 144u));
    }
    if (tid < 128) {
        cb1s[tid] = ((const float*)(ws + CB1F_B))[tid];
        bs1s[tid] = ((const float*)(ws + BS1F_B))[tid];
    }
    // persistent residual weight fragments (spatial frags reloaded per phase to stay <128 VGPR)
    bf16x8 rb0 = *(const bf16x8*)&W1Rp[n*64 + lg*8];
    bf16x8 rb1 = *(const bf16x8*)&W1Rp[n*64 + 32 + lg*8];

    uint4 pf[3];
    // initial prefetch (tile 0)
    {
        const int t0n = ck << 6;
        #pragma unroll
        for (int s = 0; s < 3; s++) {
            int idx = tid + s*512;
            uint4 v = make_uint4(0u,0u,0u,0u);
            if (idx < 1360) {
                int p = idx >> 3, seg = idx & 7;
                int P = (t0n - 1)*17 + p;
                if (P >= 0 && P < 34816)
                    v = *(const uint4*)&Y0[((size_t)b_loc*34816 + P)*64 + seg*8];
            }
            pf[s] = v;
        }
    }

    for (int tt = 0; tt < 8; tt++) {
        const int t0 = (ck << 6) + (tt << 3);
        const int Pb = (t0 - 1) * 17;

        // A: commit prefetched y0 tile
        #pragma unroll
        for (int s = 0; s < 3; s++) {
            int idx = tid + s*512;
            if (idx < 1360) {
                int p = idx >> 3, seg = idx & 7;
                *(uint4*)&bufA[p*72 + seg*8] = pf[s];
            }
        }
        __syncthreads();

        // B: prefetch next tile + W1E h0 frags + residual GEMM + sparse graph conv
        if (tt < 7) {
            const int t0n = t0 + 8;
            #pragma unroll
            for (int s = 0; s < 3; s++) {
                int idx = tid + s*512;
                uint4 v = make_uint4(0u,0u,0u,0u);
                if (idx < 1360) {
                    int p = idx >> 3, seg = idx & 7;
                    int P = (t0n - 1)*17 + p;
                    if (P >= 0 && P < 34816)
                        v = *(const uint4*)&Y0[((size_t)b_loc*34816 + P)*64 + seg*8];
                }
                pf[s] = v;
            }
        }
        bf16x8 bfh[6];
        #pragma unroll
        for (int ks = 0; ks < 6; ks++)
            bfh[ks] = *(const bf16x8*)&W1Ep[n*192 + ks*32 + lg*8];   // h=0

        f32x4 tacc[9];
        #pragma unroll
        for (int mb = 0; mb < 9; mb++) {
            const int row = mb*16 + lr + 17;
            f32x4 acc = {0.f, 0.f, 0.f, 0.f};
            acc = __builtin_amdgcn_mfma_f32_16x16x32_bf16(*(const bf16x8*)&bufA[row*72 + lg*8],      rb0, acc, 0, 0, 0);
            acc = __builtin_amdgcn_mfma_f32_16x16x32_bf16(*(const bf16x8*)&bufA[row*72 + 32 + lg*8], rb1, acc, 0, 0, 0);
            tacc[mb] = acc;
        }
        #pragma unroll
        for (int q = 0; q < 6; q++) {         // graph conv -> ygs
            int idx = tid + q*512;
            if (idx < 2720) {
                int p = idx >> 4, cg = idx & 15;
                int j = p - 17*div17(p);
                const char* rowb = (const char*)bufA + (p - j)*144 + cg*8;
                float a0=0.f, a1=0.f, a2=0.f, a3=0.f;
                #pragma unroll
                for (int i = 0; i < 8; i++) {
                    float2 e = spt[j*8 + i];
                    uint2 u = *(const uint2*)(rowb + __float_as_uint(e.y));
                    a0 += e.x * __uint_as_float(u.x << 16);
                    a1 += e.x * __uint_as_float(u.x & 0xffff0000u);
                    a2 += e.x * __uint_as_float(u.y << 16);
                    a3 += e.x * __uint_as_float(u.y & 0xffff0000u);
                }
                uint2 o; o.x = pk2(a0, a1); o.y = pk2(a2, a3);
                *(uint2*)&ygs[p*72 + cg*4] = o;
            }
        }
        __syncthreads();

        // C: s1 h0 -> bufA
        {
            bf16x8 sbA = *(const bf16x8*)&W1SBp[(nloc_s)*64 + lg*8];
            bf16x8 sbB = *(const bf16x8*)&W1SBp[(nloc_s)*64 + 32 + lg*8];
            const int mbE = sMh ? 11 : 6;
            for (int mb = sMh ? 6 : 0; mb < mbE; mb++) {
                int ra = mb*16 + lr; if (ra > 169) ra = 169;
                f32x4 sa = {0.f, 0.f, 0.f, 0.f};
                sa = __builtin_amdgcn_mfma_f32_16x16x32_bf16(*(const bf16x8*)&ygs[ra*72 + lg*8],      sbA, sa, 0, 0, 0);
                sa = __builtin_amdgcn_mfma_f32_16x16x32_bf16(*(const bf16x8*)&ygs[ra*72 + 32 + lg*8], sbB, sa, 0, 0, 0);
                const int mbase = mb*16 + lg*4;
                #pragma unroll
                for (int i = 0; i < 4; i++) {
                    int m = mbase + i;
                    if (m < 170) {
                        int P = Pb + m;
                        float v = (P >= 0 && P < 34816) ? fmaxf(sa[i] + bs1s[nloc_s], 0.f) : 0.f;
                        bufA[m*72 + nloc_s] = f2bf(v);
                    }
                }
            }
        }
        __syncthreads();

        // D: tconv h0
        #pragma unroll
        for (int mb = 0; mb < 9; mb++) {
            const int ma = mb*16 + lr;
            f32x4 acc = tacc[mb];
            #pragma unroll
            for (int ks = 0; ks < 6; ks++) {
                int row = ma + (ks >> 1)*17; if (row > 169) row = 169;
                const int c0 = ((ks & 1) << 5) + lg*8;
                acc = __builtin_amdgcn_mfma_f32_16x16x32_bf16(
                    *(const bf16x8*)&bufA[row*72 + c0], bfh[ks], acc, 0, 0, 0);
            }
            tacc[mb] = acc;
        }
        __syncthreads();

        // E: W1E h1 frags + s1 h1 -> bufA
        #pragma unroll
        for (int ks = 0; ks < 6; ks++)
            bfh[ks] = *(const bf16x8*)&W1Ep[(128 + n)*192 + ks*32 + lg*8];
        {
            bf16x8 sbA = *(const bf16x8*)&W1SBp[(64 + nloc_s)*64 + lg*8];
            bf16x8 sbB = *(const bf16x8*)&W1SBp[(64 + nloc_s)*64 + 32 + lg*8];
            const int mbE = sMh ? 11 : 6;
            for (int mb = sMh ? 6 : 0; mb < mbE; mb++) {
                int ra = mb*16 + lr; if (ra > 169) ra = 169;
                f32x4 sa = {0.f, 0.f, 0.f, 0.f};
                sa = __builtin_amdgcn_mfma_f32_16x16x32_bf16(*(const bf16x8*)&ygs[ra*72 + lg*8],      sbA, sa, 0, 0, 0);
                sa = __builtin_amdgcn_mfma_f32_16x16x32_bf16(*(const bf16x8*)&ygs[ra*72 + 32 + lg*8], sbB, sa, 0, 0, 0);
                const int mbase = mb*16 + lg*4;
                #pragma unroll
                for (int i = 0; i < 4; i++) {
                    int m = mbase + i;
                    if (m < 170) {
                        int P = Pb + m;
                        float v = (P >= 0 && P < 34816) ? fmaxf(sa[i] + bs1s[64 + nloc_s], 0.f) : 0.f;
                        bufA[m*72 + nloc_s] = f2bf(v);
                    }
                }
            }
        }
        __syncthreads();

        // F1: tconv h1
        #pragma unroll
        for (int mb = 0; mb < 9; mb++) {
            const int ma = mb*16 + lr;
            f32x4 acc = tacc[mb];
            #pragma unroll
            for (int ks = 0; ks < 6; ks++) {
                int row = ma + (ks >> 1)*17; if (row > 169) row = 169;
                const int c0 = ((ks & 1) << 5) + lg*8;
                acc = __builtin_amdgcn_mfma_f32_16x16x32_bf16(
                    *(const bf16x8*)&bufA[row*72 + c0], bfh[ks], acc, 0, 0, 0);
            }
            tacc[mb] = acc;
        }
        __syncthreads();

        // F2: y1 = relu(tconv + resid + bias) -> overlay buffer [136][132]
        #pragma unroll
        for (int mb = 0; mb < 9; mb++) {
            const int mbase = mb*16 + lg*4;
            #pragma unroll
            for (int i = 0; i < 4; i++) {
                int m = mbase + i;
                if (m < 136)
                    y1[m*132 + n] = f2bf(fmaxf(tacc[mb][i] + cb1s[n], 0.f));
            }
        }
        __syncthreads();

        // G: mean over J -> MEANS (bf16)
        {
            const int t = tid >> 6, n2 = (tid & 63) * 2;
            float s0v = 0.f, s1v = 0.f;
            #pragma unroll
            for (int jj = 0; jj < 17; jj++) {
                unsigned u = *(const unsigned*)&y1[(t*17 + jj)*132 + n2];
                s0v += __uint_as_float(u << 16);
                s1v += __uint_as_float(u & 0xffff0000u);
            }
            const float sc = 1.f / 17.f;
            *(unsigned*)&MEANS[((size_t)(b_loc*2048 + t0 + t))*128 + n2] = pk2(s0v*sc, s1v*sc);
        }
        __syncthreads();
    }
}

// ---------------- projection: [chunk*2048,128] x [128,128] ----------------
__launch_bounds__(256, 3)
__global__ void proj_kernel(const unsigned short* __restrict__ MEANS,
                            const unsigned char* __restrict__ ws,
                            const float* __restrict__ projb,
                            float* __restrict__ outp, int bt_base) {
    __shared__ __align__(16) unsigned short As[128*136];
    __shared__ float pbs[128];

    const int tid = threadIdx.x;
    const int m0 = blockIdx.x * 128;
    const int w = tid >> 6, l = tid & 63, lr = l & 15, lg = l >> 4;
    const unsigned short* PROJW = (const unsigned short*)(ws + PROJW_B);

    if (tid < 128) pbs[tid] = projb[tid];
    #pragma unroll
    for (int it = 0; it < 8; it++) {
        int idx = tid + it*256;
        int m = idx >> 4, seg = idx & 15;
        *(uint4*)&As[m*136 + seg*8] = *(const uint4*)&MEANS[(size_t)(m0 + m)*128 + seg*8];
    }
    __syncthreads();

    f32x4 acc[8][2];
    #pragma unroll
    for (int et = 0; et < 8; et++) {
        const int e = et*16 + lr;
        bf16x8 bf[4];
        #pragma unroll
        for (int kf = 0; kf < 4; kf++)
            bf[kf] = *(const bf16x8*)&PROJW[e*128 + kf*32 + lg*8];
        #pragma unroll
        for (int m2 = 0; m2 < 2; m2++) {
            const int ra = (w*2 + m2)*16 + lr;
            f32x4 a = {0.f, 0.f, 0.f, 0.f};
            #pragma unroll
            for (int kf = 0; kf < 4; kf++)
                a = __builtin_amdgcn_mfma_f32_16x16x32_bf16(
                    *(const bf16x8*)&As[ra*136 + kf*32 + lg*8], bf[kf], a, 0, 0, 0);
            acc[et][m2] = a;
        }
    }
    #pragma unroll
    for (int et = 0; et < 8; et++) {
        const int e = et*16 + lr;
        const float pb = pbs[e];
        #pragma unroll
        for (int m2 = 0; m2 < 2; m2++) {
            const int mbase = (w*2 + m2)*16 + lg*4;
            #pragma unroll
            for (int i = 0; i < 4; i++) {
                const int m = mbase + i;
                outp[(size_t)(bt_base + m0 + m)*128 + e] = acc[et][m2][i] + pb;
            }
        }
    }
}

extern "C" void kernel_launch(void* const* d_in, const int* in_sizes, int n_in,
                              void* d_out, int out_size, void* d_ws, size_t ws_size,
                              hipStream_t stream) {
    const float* x     = (const float*)d_in[0];
    const float* adj   = (const float*)d_in[1];
    const float* projb = (const float*)d_in[39];
    unsigned char* ws  = (unsigned char*)d_ws;

    PrepArgs pa;
    pa.sw0 = (const float*)d_in[2];  pa.sb0  = (const float*)d_in[3];
    pa.sg0 = (const float*)d_in[4];  pa.sbb0 = (const float*)d_in[5];
    pa.sm0 = (const float*)d_in[6];  pa.sv0  = (const float*)d_in[7];
    pa.tw0 = (const float*)d_in[8];  pa.tb0  = (const float*)d_in[9];
    pa.tg0 = (const float*)d_in[10]; pa.tbb0 = (const float*)d_in[11];
    pa.tm0 = (const float*)d_in[12]; pa.tv0  = (const float*)d_in[13];
    pa.rw0 = (const float*)d_in[14]; pa.rb0  = (const float*)d_in[15];
    pa.rg0 = (const float*)d_in[16]; pa.rbb0 = (const float*)d_in[17];
    pa.rm0 = (const float*)d_in[18]; pa.rv0  = (const float*)d_in[19];
    pa.sw1 = (const float*)d_in[20]; pa.sb1  = (const float*)d_in[21];
    pa.sg1 = (const float*)d_in[22]; pa.sbb1 = (const float*)d_in[23];
    pa.sm1 = (const float*)d_in[24]; pa.sv1  = (const float*)d_in[25];
    pa.tw1 = (const float*)d_in[26]; pa.tb1  = (const float*)d_in[27];
    pa.tg1 = (const float*)d_in[28]; pa.tbb1 = (const float*)d_in[29];
    pa.tm1 = (const float*)d_in[30]; pa.tv1  = (const float*)d_in[31];
    pa.rw1 = (const float*)d_in[32]; pa.rb1  = (const float*)d_in[33];
    pa.rg1 = (const float*)d_in[34]; pa.rbb1 = (const float*)d_in[35];
    pa.rm1 = (const float*)d_in[36]; pa.rv1  = (const float*)d_in[37];
    pa.projw = (const float*)d_in[38];
    pa.adj = adj;
    pa.ws = ws;

    prep_kernel<<<dim3(369), dim3(256), 0, stream>>>(pa);

    int chunk = 16;
    while (chunk > 1 &&
           (size_t)MEANS_B + (size_t)chunk * (524288ull + Y0_PERB) > ws_size)
        chunk >>= 1;

    unsigned short* MEANSp = (unsigned short*)(ws + MEANS_B);
    unsigned short* Y0p    = (unsigned short*)(ws + MEANS_B + (size_t)chunk * 524288ull);

    for (int cb = 0; cb < 16; cb += chunk) {
        b0_kernel<<<dim3(chunk * 256), dim3(256), 0, stream>>>(x, ws, Y0p, cb);
        b1_kernel<<<dim3(chunk * 32), dim3(512), 0, stream>>>(ws, Y0p, MEANSp);
        proj_kernel<<<dim3(chunk * 16), dim3(256), 0, stream>>>(MEANSp, ws, projb, (float*)d_out, cb * 2048);
    }
}

// Round 4
// 370.520 us; speedup vs baseline: 1.4443x; 1.0671x over previous
//
#include <hip/hip_runtime.h>
#include <hip/hip_bf16.h>
#include <stdint.h>

typedef __attribute__((ext_vector_type(8))) short bf16x8;
typedef __attribute__((ext_vector_type(4))) float f32x4;

#define EPSB 1e-5f

// ---------------- workspace byte offsets ----------------
#define W0TE_B   0u          // [64][192] bf16, k = tap*64 + c
#define W1SB_B   24576u      // [128][64] bf16
#define W1E_B    40960u      // [2][128][192] bf16
#define W1R_B    139264u     // [128][64] bf16
#define PROJW_B  155648u     // [128][128] bf16
#define WS0F_B   188416u     // [64][4] f32
#define WR0F_B   189440u     // [64][4] f32
#define BS0F_B   190464u     // [64] f32
#define CB0F_B   190720u     // [64] f32
#define BS1F_B   190976u     // [128] f32
#define CB1F_B   191488u     // [128] f32
#define SPT_B    192000u     // [17][8] float2 {a, k-as-uint-bits}
#define MEANS_B  193536u
#define MEANS_PERB 524288ull // 2048*128*2
#define Y0_PERB  4456448ull  // 2048*17*64*2

__device__ __forceinline__ float bf2f(unsigned int u16v) {
    union { unsigned int i; float f; } v; v.i = u16v << 16; return v.f;
}
__device__ __forceinline__ unsigned short f2bf(float f) {
    unsigned int x = __float_as_uint(f);
    x = x + 0x7fffu + ((x >> 16) & 1u);   // RNE
    return (unsigned short)(x >> 16);
}
__device__ __forceinline__ unsigned pk2(float a, float b) {
    union { __hip_bfloat162 h; unsigned u; } v;
    v.h = __float22bfloat162_rn(make_float2(a, b));
    return v.u;
}
__device__ __forceinline__ int div17(int p) { return (p * 241) >> 12; }  // valid p<=255

struct PrepArgs {
    const float *sw0,*sb0,*sg0,*sbb0,*sm0,*sv0;
    const float *tw0,*tb0,*tg0,*tbb0,*tm0,*tv0;
    const float *rw0,*rb0,*rg0,*rbb0,*rm0,*rv0;
    const float *sw1,*sb1,*sg1,*sbb1,*sm1,*sv1;
    const float *tw1,*tb1,*tg1,*tbb1,*tm1,*tv1;
    const float *rw1,*rb1,*rg1,*rbb1,*rm1,*rv1;
    const float *projw;
    const float *adj;
    unsigned char* ws;
};

__global__ void prep_kernel(PrepArgs a) {
    const int g = blockIdx.x * 256 + threadIdx.x;
    unsigned short* W0TE  = (unsigned short*)(a.ws + W0TE_B);
    unsigned short* W1SBp = (unsigned short*)(a.ws + W1SB_B);
    unsigned short* W1Ep  = (unsigned short*)(a.ws + W1E_B);
    unsigned short* W1Rp  = (unsigned short*)(a.ws + W1R_B);
    unsigned short* PROJW = (unsigned short*)(a.ws + PROJW_B);
    float* WS0F = (float*)(a.ws + WS0F_B);
    float* WR0F = (float*)(a.ws + WR0F_B);
    float* BS0F = (float*)(a.ws + BS0F_B);
    float* CB0F = (float*)(a.ws + CB0F_B);
    float* BS1F = (float*)(a.ws + BS1F_B);
    float* CB1F = (float*)(a.ws + CB1F_B);
    float2* SPT = (float2*)(a.ws + SPT_B);

    if (g < 64) {
        int o = g;
        float scs = a.sg0[o] / sqrtf(a.sv0[o] + EPSB);
        BS0F[o] = scs * (a.sb0[o] - a.sm0[o]) + a.sbb0[o];
        for (int c = 0; c < 4; c++) WS0F[o*4+c] = (c < 3) ? scs * a.sw0[o*3+c] : 0.f;
        float tct = a.tg0[o] / sqrtf(a.tv0[o] + EPSB);
        float rcr = a.rg0[o] / sqrtf(a.rv0[o] + EPSB);
        CB0F[o] = tct * (a.tb0[o] - a.tm0[o]) + a.tbb0[o]
                + rcr * (a.rb0[o] - a.rm0[o]) + a.rbb0[o];
        for (int c = 0; c < 4; c++) WR0F[o*4+c] = (c < 3) ? rcr * a.rw0[o*3+c] : 0.f;
    } else if (g < 192) {
        int o = g - 64;
        float scs = a.sg1[o] / sqrtf(a.sv1[o] + EPSB);
        BS1F[o] = scs * (a.sb1[o] - a.sm1[o]) + a.sbb1[o];
        float tct = a.tg1[o] / sqrtf(a.tv1[o] + EPSB);
        float rcr = a.rg1[o] / sqrtf(a.rv1[o] + EPSB);
        CB1F[o] = tct * (a.tb1[o] - a.tm1[o]) + a.tbb1[o]
                + rcr * (a.rb1[o] - a.rm1[o]) + a.rbb1[o];
    } else if (g < 12480) {                   // W0TE: 64*192
        int idx = g - 192;
        int o = idx / 192, k = idx % 192, tap = k >> 6, c = k & 63;
        float tct = a.tg0[o] / sqrtf(a.tv0[o] + EPSB);
        W0TE[o*192 + k] = f2bf(tct * a.tw0[(o*64 + c)*3 + tap]);
    } else if (g < 20672) {                   // W1SB: 128*64
        int idx = g - 12480;
        int o = idx >> 6, c = idx & 63;
        float scs = a.sg1[o] / sqrtf(a.sv1[o] + EPSB);
        W1SBp[o*64 + c] = f2bf(scs * a.sw1[o*64 + c]);
    } else if (g < 69824) {                   // W1E: 2*128*192
        int idx = g - 20672;
        int h = idx / 24576, r = idx % 24576;
        int o = r / 192, k = r % 192, tap = k >> 6, c = (h << 6) + (k & 63);
        float tct = a.tg1[o] / sqrtf(a.tv1[o] + EPSB);
        W1Ep[(h*128 + o)*192 + k] = f2bf(tct * a.tw1[(o*128 + c)*3 + tap]);
    } else if (g < 78016) {                   // W1R: 128*64
        int idx = g - 69824;
        int o = idx >> 6, c = idx & 63;
        float rcr = a.rg1[o] / sqrtf(a.rv1[o] + EPSB);
        W1Rp[o*64 + c] = f2bf(rcr * a.rw1[o*64 + c]);
    } else if (g < 94400) {                   // PROJW: 128*128
        int idx = g - 78016;
        PROJW[idx] = f2bf(a.projw[idx]);
    } else if (g < 94417) {                   // sparse adj columns
        int j = g - 94400;
        int cnt = 0;
        for (int k = 0; k < 17; k++) {
            float v = a.adj[k*17 + j];
            if (v != 0.0f && cnt < 8) {
                SPT[j*8 + cnt] = make_float2(v, __uint_as_float((unsigned)k));
                cnt++;
            }
        }
        for (; cnt < 8; cnt++) SPT[j*8 + cnt] = make_float2(0.f, __uint_as_float(0u));
    }
}

// ---------------- block 0: 3 -> 64, T-tile 8; also emits yg = graphconv(y0) ----------------
__launch_bounds__(256, 3)
__global__ void b0_kernel(const float* __restrict__ x,
                          const unsigned char* __restrict__ ws,
                          unsigned short* __restrict__ Y0,
                          unsigned short* __restrict__ YG, int b0base) {
    __shared__ float xt[510];                 // [3][170]
    __shared__ float xg[510];
    __shared__ float2 sptA[136];              // offsets *4 (f32 rows)
    __shared__ float2 sptB[136];              // offsets *144 (bf16 [.][72] rows)
    __shared__ float Ws0s[256], Wr0s[256], bs0s[64], cb0s[64];
    __shared__ __align__(16) unsigned short s0[170*72];
    __shared__ __align__(16) unsigned short yst[136*72];

    const int tid = threadIdx.x;
    const int b_loc = blockIdx.x >> 8;
    const int b = b0base + b_loc;
    const int t0 = (blockIdx.x & 255) << 3;
    const int Pb = (t0 - 1) * 17;

    const int w = tid >> 6, l = tid & 63, lr = l & 15, lg = l >> 4;
    const int n = w*16 + lr;

    const unsigned short* W0TE = (const unsigned short*)(ws + W0TE_B);
    bf16x8 bfr[6];
    #pragma unroll
    for (int ks = 0; ks < 6; ks++)
        bfr[ks] = *(const bf16x8*)&W0TE[n*192 + ks*32 + lg*8];

    if (tid < 136) {
        float2 raw = ((const float2*)(ws + SPT_B))[tid];
        sptA[tid] = make_float2(raw.x, __uint_as_float(__float_as_uint(raw.y) * 4u));
        sptB[tid] = make_float2(raw.x, __uint_as_float(__float_as_uint(raw.y) * 144u));
    }
    Ws0s[tid] = ((const float*)(ws + WS0F_B))[tid];
    Wr0s[tid] = ((const float*)(ws + WR0F_B))[tid];
    if (tid < 64) {
        bs0s[tid] = ((const float*)(ws + BS0F_B))[tid];
        cb0s[tid] = ((const float*)(ws + CB0F_B))[tid];
    }
    #pragma unroll
    for (int it = 0; it < 2; it++) {          // x -> LDS
        int idx = tid + it*256;
        if (idx < 510) {
            int c = idx / 170, r = idx - c*170;
            int P = Pb + r;
            float v = 0.f;
            if (P >= 0 && P < 34816) v = x[(size_t)(b*3 + c)*34816 + P];
            xt[idx] = v;
        }
    }
    __syncthreads();
    #pragma unroll
    for (int it = 0; it < 2; it++) {          // sparse graph conv on x
        int idx = tid + it*256;
        if (idx < 510) {
            int c = idx / 170, r = idx - c*170;
            int j = r - 17*div17(r);
            const char* rowb = (const char*)&xt[c*170 + (r - j)];
            float acc = 0.f;
            #pragma unroll
            for (int i = 0; i < 8; i++) {
                float2 e = sptA[j*8 + i];
                acc += e.x * *(const float*)(rowb + __float_as_uint(e.y));
            }
            xg[idx] = acc;
        }
    }
    __syncthreads();
    #pragma unroll
    for (int it = 0; it < 11; it++) {         // s0 = relu(conv1x1(xg)), zero OOB rows
        int idx = tid + it*256;
        if (idx < 2720) {
            int r = idx >> 4, cg = idx & 15, o0 = cg*4;
            int P = Pb + r;
            uint2 pkv = make_uint2(0u, 0u);
            if (P >= 0 && P < 34816) {
                float a0 = xg[r], a1 = xg[170 + r], a2 = xg[340 + r];
                float v0 = fmaxf(bs0s[o0]   + Ws0s[(o0  )*4]*a0 + Ws0s[(o0  )*4+1]*a1 + Ws0s[(o0  )*4+2]*a2, 0.f);
                float v1 = fmaxf(bs0s[o0+1] + Ws0s[(o0+1)*4]*a0 + Ws0s[(o0+1)*4+1]*a1 + Ws0s[(o0+1)*4+2]*a2, 0.f);
                float v2 = fmaxf(bs0s[o0+2] + Ws0s[(o0+2)*4]*a0 + Ws0s[(o0+2)*4+1]*a1 + Ws0s[(o0+2)*4+2]*a2, 0.f);
                float v3 = fmaxf(bs0s[o0+3] + Ws0s[(o0+3)*4]*a0 + Ws0s[(o0+3)*4+1]*a1 + Ws0s[(o0+3)*4+2]*a2, 0.f);
                pkv.x = pk2(v0, v1); pkv.y = pk2(v2, v3);
            }
            *(uint2*)&s0[r*72 + o0] = pkv;
        }
    }
    __syncthreads();
    {   // tconv GEMM + residual -> yst
        const float wr0 = Wr0s[n*4], wr1 = Wr0s[n*4+1], wr2 = Wr0s[n*4+2];
        const float cbn = cb0s[n];
        for (int mb = 0; mb < 9; mb++) {
            const int ra = mb*16 + lr;
            f32x4 acc = {0.f, 0.f, 0.f, 0.f};
            #pragma unroll
            for (int ks = 0; ks < 6; ks++) {
                int row = ra + (ks >> 1)*17; if (row > 169) row = 169;
                const int c0 = ((ks & 1) << 5) + lg*8;
                acc = __builtin_amdgcn_mfma_f32_16x16x32_bf16(
                    *(const bf16x8*)&s0[row*72 + c0], bfr[ks], acc, 0, 0, 0);
            }
            const int mbase = mb*16 + lg*4;
            #pragma unroll
            for (int i = 0; i < 4; i++) {
                const int m = mbase + i;
                if (m < 136) {
                    float v = acc[i] + cbn + wr0*xt[m+17] + wr1*xt[170+m+17] + wr2*xt[340+m+17];
                    yst[m*72 + n] = f2bf(fmaxf(v, 0.f));
                }
            }
        }
    }
    __syncthreads();
    #pragma unroll
    for (int it = 0; it < 5; it++) {          // Y0 store (contiguous in m)
        int idx = tid + it*256;
        if (idx < 1088) {
            int m = idx >> 3, seg = idx & 7;
            uint4 v = *(const uint4*)&yst[m*72 + seg*8];
            *(uint4*)&Y0[((size_t)b_loc*34816 + t0*17 + m)*64 + seg*8] = v;
        }
    }
    #pragma unroll
    for (int it = 0; it < 9; it++) {          // yg = graphconv(yst), reg->global (no halo needed)
        int idx = tid + it*256;
        if (idx < 2176) {
            int p = idx >> 4, cg = idx & 15;
            int j = p - 17*div17(p);
            const char* rowb = (const char*)yst + (p - j)*144 + cg*8;
            float a0=0.f, a1=0.f, a2=0.f, a3=0.f;
            #pragma unroll
            for (int i = 0; i < 8; i++) {
                float2 e = sptB[j*8 + i];
                uint2 u = *(const uint2*)(rowb + __float_as_uint(e.y));
                a0 += e.x * __uint_as_float(u.x << 16);
                a1 += e.x * __uint_as_float(u.x & 0xffff0000u);
                a2 += e.x * __uint_as_float(u.y << 16);
                a3 += e.x * __uint_as_float(u.y & 0xffff0000u);
            }
            uint2 o; o.x = pk2(a0, a1); o.y = pk2(a2, a3);
            *(uint2*)&YG[((size_t)b_loc*34816 + t0*17 + p)*64 + cg*4] = o;
        }
    }
}

// ---------------- block 1: 64 -> 128 + in-reg mean; 64 blocks/batch x 4 tiles ----------------
__launch_bounds__(512, 2)
__global__ void b1_kernel(const unsigned char* __restrict__ ws,
                          const unsigned short* __restrict__ Y0,
                          const unsigned short* __restrict__ YG,
                          unsigned short* __restrict__ MEANS) {
    __shared__ __align__(16) unsigned short smem[36720];
    unsigned short* ybuf  = smem;             // [170][72]; y0 center rows 17..152, later s1 h1
    unsigned short* ygbuf = smem + 12240;     // [170][72] yg halo tile
    unsigned short* s0buf = smem + 24480;     // [170][72] s1 h0
    __shared__ float cb1s[128], bs1s[128];

    const int tid = threadIdx.x;
    const int b_loc = blockIdx.x >> 6;
    const int ck = blockIdx.x & 63;

    const unsigned short* W1SBp = (const unsigned short*)(ws + W1SB_B);
    const unsigned short* W1Ep  = (const unsigned short*)(ws + W1E_B);
    const unsigned short* W1Rp  = (const unsigned short*)(ws + W1R_B);

    const int w = tid >> 6, l = tid & 63, lr = l & 15, lg = l >> 4;
    const int n = w*16 + lr;
    const int sNt = w & 3, sMh = w >> 2;
    const int nloc_s = sNt*16 + lr;

    if (tid < 128) {
        cb1s[tid] = ((const float*)(ws + CB1F_B))[tid];
        bs1s[tid] = ((const float*)(ws + BS1F_B))[tid];
    }
    bf16x8 rb0 = *(const bf16x8*)&W1Rp[n*64 + lg*8];
    bf16x8 rb1 = *(const bf16x8*)&W1Rp[n*64 + 32 + lg*8];

    uint4 pf[5];
    auto PF = [&](int t0n) {
        const int Pb = t0n*17 - 17;
        #pragma unroll
        for (int s = 0; s < 5; s++) {
            int idx = tid + s*512;
            uint4 v = make_uint4(0u,0u,0u,0u);
            if (idx < 1360) {                 // yg halo rows 0..169
                int p = idx >> 3, seg = idx & 7;
                int P = Pb + p;
                if (P >= 0 && P < 34816)
                    v = *(const uint4*)&YG[((size_t)b_loc*34816 + P)*64 + seg*8];
            } else if (idx < 2448) {          // y0 center rows 0..135
                int p = (idx - 1360) >> 3, seg = (idx - 1360) & 7;
                v = *(const uint4*)&Y0[((size_t)b_loc*34816 + t0n*17 + p)*64 + seg*8];
            }
            pf[s] = v;
        }
    };
    PF(ck << 5);

    for (int tt = 0; tt < 4; tt++) {
        const int t0 = (ck << 5) + (tt << 3);
        const int Pb = (t0 - 1) * 17;

        // ---- P0: commit prefetched tile ----
        #pragma unroll
        for (int s = 0; s < 5; s++) {
            int idx = tid + s*512;
            if (idx < 1360) {
                int p = idx >> 3, seg = idx & 7;
                *(uint4*)&ygbuf[p*72 + seg*8] = pf[s];
            } else if (idx < 2448) {
                int p = (idx - 1360) >> 3, seg = (idx - 1360) & 7;
                *(uint4*)&ybuf[(17 + p)*72 + seg*8] = pf[s];
            }
        }
        __syncthreads();

        // ---- P1: next-tile prefetch + residual GEMM (ybuf) + s1 h0 (ygbuf -> s0buf) ----
        if (tt < 3) PF(t0 + 8);

        f32x4 tacc[9];
        #pragma unroll
        for (int mb = 0; mb < 9; mb++) {
            const int row = 17 + mb*16 + lr;  // rows >152 are garbage -> discarded outputs only
            f32x4 acc = {0.f, 0.f, 0.f, 0.f};
            acc = __builtin_amdgcn_mfma_f32_16x16x32_bf16(*(const bf16x8*)&ybuf[row*72 + lg*8],      rb0, acc, 0, 0, 0);
            acc = __builtin_amdgcn_mfma_f32_16x16x32_bf16(*(const bf16x8*)&ybuf[row*72 + 32 + lg*8], rb1, acc, 0, 0, 0);
            tacc[mb] = acc;
        }
        {
            bf16x8 sbA = *(const bf16x8*)&W1SBp[(nloc_s)*64 + lg*8];
            bf16x8 sbB = *(const bf16x8*)&W1SBp[(nloc_s)*64 + 32 + lg*8];
            const float bias = bs1s[nloc_s];
            const int mbE = sMh ? 11 : 6;
            for (int mb = sMh ? 6 : 0; mb < mbE; mb++) {
                int ra = mb*16 + lr; if (ra > 169) ra = 169;
                f32x4 sa = {0.f, 0.f, 0.f, 0.f};
                sa = __builtin_amdgcn_mfma_f32_16x16x32_bf16(*(const bf16x8*)&ygbuf[ra*72 + lg*8],      sbA, sa, 0, 0, 0);
                sa = __builtin_amdgcn_mfma_f32_16x16x32_bf16(*(const bf16x8*)&ygbuf[ra*72 + 32 + lg*8], sbB, sa, 0, 0, 0);
                const int mbase = mb*16 + lg*4;
                #pragma unroll
                for (int i = 0; i < 4; i++) {
                    int m = mbase + i;
                    if (m < 170) {
                        int P = Pb + m;
                        float v = (P >= 0 && P < 34816) ? fmaxf(sa[i] + bias, 0.f) : 0.f;
                        s0buf[m*72 + nloc_s] = f2bf(v);
                    }
                }
            }
        }
        __syncthreads();

        // ---- P2: tconv h0 (s0buf) + s1 h1 (ygbuf -> ybuf) ----
        {
            bf16x8 bfh[6];
            #pragma unroll
            for (int ks = 0; ks < 6; ks++)
                bfh[ks] = *(const bf16x8*)&W1Ep[n*192 + ks*32 + lg*8];
            #pragma unroll
            for (int mb = 0; mb < 9; mb++) {
                const int ma = mb*16 + lr;
                f32x4 acc = tacc[mb];
                #pragma unroll
                for (int ks = 0; ks < 6; ks++) {
                    int row = ma + (ks >> 1)*17; if (row > 169) row = 169;
                    const int c0 = ((ks & 1) << 5) + lg*8;
                    acc = __builtin_amdgcn_mfma_f32_16x16x32_bf16(
                        *(const bf16x8*)&s0buf[row*72 + c0], bfh[ks], acc, 0, 0, 0);
                }
                tacc[mb] = acc;
            }
        }
        {
            bf16x8 sbA = *(const bf16x8*)&W1SBp[(64 + nloc_s)*64 + lg*8];
            bf16x8 sbB = *(const bf16x8*)&W1SBp[(64 + nloc_s)*64 + 32 + lg*8];
            const float bias = bs1s[64 + nloc_s];
            const int mbE = sMh ? 11 : 6;
            for (int mb = sMh ? 6 : 0; mb < mbE; mb++) {
                int ra = mb*16 + lr; if (ra > 169) ra = 169;
                f32x4 sa = {0.f, 0.f, 0.f, 0.f};
                sa = __builtin_amdgcn_mfma_f32_16x16x32_bf16(*(const bf16x8*)&ygbuf[ra*72 + lg*8],      sbA, sa, 0, 0, 0);
                sa = __builtin_amdgcn_mfma_f32_16x16x32_bf16(*(const bf16x8*)&ygbuf[ra*72 + 32 + lg*8], sbB, sa, 0, 0, 0);
                const int mbase = mb*16 + lg*4;
                #pragma unroll
                for (int i = 0; i < 4; i++) {
                    int m = mbase + i;
                    if (m < 170) {
                        int P = Pb + m;
                        float v = (P >= 0 && P < 34816) ? fmaxf(sa[i] + bias, 0.f) : 0.f;
                        ybuf[m*72 + nloc_s] = f2bf(v);
                    }
                }
            }
        }
        __syncthreads();

        // ---- P3: tconv h1 (ybuf) + relu epilogue + in-register mean over J + MEANS store ----
        {
            bf16x8 bfh[6];
            #pragma unroll
            for (int ks = 0; ks < 6; ks++)
                bfh[ks] = *(const bf16x8*)&W1Ep[(128 + n)*192 + ks*32 + lg*8];
            #pragma unroll
            for (int mb = 0; mb < 9; mb++) {
                const int ma = mb*16 + lr;
                f32x4 acc = tacc[mb];
                #pragma unroll
                for (int ks = 0; ks < 6; ks++) {
                    int row = ma + (ks >> 1)*17; if (row > 169) row = 169;
                    const int c0 = ((ks & 1) << 5) + lg*8;
                    acc = __builtin_amdgcn_mfma_f32_16x16x32_bf16(
                        *(const bf16x8*)&ybuf[row*72 + c0], bfh[ks], acc, 0, 0, 0);
                }
                tacc[mb] = acc;
            }
        }
        {
            const float cb = cb1s[n];
            #pragma unroll
            for (int t = 0; t < 8; t++) {
                float s = 0.f;
                #pragma unroll
                for (int mb = 0; mb < 9; mb++) {
                    #pragma unroll
                    for (int i = 0; i < 4; i++) {
                        const int mlo = mb*16 + i;          // lane's m = mlo + lg*4
                        if (mlo + 12 >= t*17 && mlo <= t*17 + 16 && mlo < 136) {
                            int m = mlo + lg*4;
                            bool in = (m >= t*17) && (m <= t*17 + 16) && (m < 136);
                            float v = fmaxf(tacc[mb][i] + cb, 0.f);
                            s += in ? v : 0.f;
                        }
                    }
                }
                s += __shfl_xor(s, 16, 64);
                s += __shfl_xor(s, 32, 64);
                if ((t & 3) == lg)
                    MEANS[((size_t)(b_loc*2048 + t0 + t))*128 + n] = f2bf(s * (1.f/17.f));
            }
        }
        __syncthreads();
    }
}

// ---------------- projection: [chunk*2048,128] x [128,128] ----------------
__launch_bounds__(256, 3)
__global__ void proj_kernel(const unsigned short* __restrict__ MEANS,
                            const unsigned char* __restrict__ ws,
                            const float* __restrict__ projb,
                            float* __restrict__ outp, int bt_base) {
    __shared__ __align__(16) unsigned short As[128*136];
    __shared__ float pbs[128];

    const int tid = threadIdx.x;
    const int m0 = blockIdx.x * 128;
    const int w = tid >> 6, l = tid & 63, lr = l & 15, lg = l >> 4;
    const unsigned short* PROJW = (const unsigned short*)(ws + PROJW_B);

    if (tid < 128) pbs[tid] = projb[tid];
    #pragma unroll
    for (int it = 0; it < 8; it++) {
        int idx = tid + it*256;
        int m = idx >> 4, seg = idx & 15;
        *(uint4*)&As[m*136 + seg*8] = *(const uint4*)&MEANS[(size_t)(m0 + m)*128 + seg*8];
    }
    __syncthreads();

    f32x4 acc[8][2];
    #pragma unroll
    for (int et = 0; et < 8; et++) {
        const int e = et*16 + lr;
        bf16x8 bf[4];
        #pragma unroll
        for (int kf = 0; kf < 4; kf++)
            bf[kf] = *(const bf16x8*)&PROJW[e*128 + kf*32 + lg*8];
        #pragma unroll
        for (int m2 = 0; m2 < 2; m2++) {
            const int ra = (w*2 + m2)*16 + lr;
            f32x4 a = {0.f, 0.f, 0.f, 0.f};
            #pragma unroll
            for (int kf = 0; kf < 4; kf++)
                a = __builtin_amdgcn_mfma_f32_16x16x32_bf16(
                    *(const bf16x8*)&As[ra*136 + kf*32 + lg*8], bf[kf], a, 0, 0, 0);
            acc[et][m2] = a;
        }
    }
    #pragma unroll
    for (int et = 0; et < 8; et++) {
        const int e = et*16 + lr;
        const float pb = pbs[e];
        #pragma unroll
        for (int m2 = 0; m2 < 2; m2++) {
            const int mbase = (w*2 + m2)*16 + lg*4;
            #pragma unroll
            for (int i = 0; i < 4; i++) {
                const int m = mbase + i;
                outp[(size_t)(bt_base + m0 + m)*128 + e] = acc[et][m2][i] + pb;
            }
        }
    }
}

extern "C" void kernel_launch(void* const* d_in, const int* in_sizes, int n_in,
                              void* d_out, int out_size, void* d_ws, size_t ws_size,
                              hipStream_t stream) {
    const float* x     = (const float*)d_in[0];
    const float* adj   = (const float*)d_in[1];
    const float* projb = (const float*)d_in[39];
    unsigned char* ws  = (unsigned char*)d_ws;

    PrepArgs pa;
    pa.sw0 = (const float*)d_in[2];  pa.sb0  = (const float*)d_in[3];
    pa.sg0 = (const float*)d_in[4];  pa.sbb0 = (const float*)d_in[5];
    pa.sm0 = (const float*)d_in[6];  pa.sv0  = (const float*)d_in[7];
    pa.tw0 = (const float*)d_in[8];  pa.tb0  = (const float*)d_in[9];
    pa.tg0 = (const float*)d_in[10]; pa.tbb0 = (const float*)d_in[11];
    pa.tm0 = (const float*)d_in[12]; pa.tv0  = (const float*)d_in[13];
    pa.rw0 = (const float*)d_in[14]; pa.rb0  = (const float*)d_in[15];
    pa.rg0 = (const float*)d_in[16]; pa.rbb0 = (const float*)d_in[17];
    pa.rm0 = (const float*)d_in[18]; pa.rv0  = (const float*)d_in[19];
    pa.sw1 = (const float*)d_in[20]; pa.sb1  = (const float*)d_in[21];
    pa.sg1 = (const float*)d_in[22]; pa.sbb1 = (const float*)d_in[23];
    pa.sm1 = (const float*)d_in[24]; pa.sv1  = (const float*)d_in[25];
    pa.tw1 = (const float*)d_in[26]; pa.tb1  = (const float*)d_in[27];
    pa.tg1 = (const float*)d_in[28]; pa.tbb1 = (const float*)d_in[29];
    pa.tm1 = (const float*)d_in[30]; pa.tv1  = (const float*)d_in[31];
    pa.rw1 = (const float*)d_in[32]; pa.rb1  = (const float*)d_in[33];
    pa.rg1 = (const float*)d_in[34]; pa.rbb1 = (const float*)d_in[35];
    pa.rm1 = (const float*)d_in[36]; pa.rv1  = (const float*)d_in[37];
    pa.projw = (const float*)d_in[38];
    pa.adj = adj;
    pa.ws = ws;

    prep_kernel<<<dim3(369), dim3(256), 0, stream>>>(pa);

    // per-batch scratch: MEANS + Y0 + YG
    const size_t perb = MEANS_PERB + 2ull * Y0_PERB;
    int chunk = 16;
    while (chunk > 1 && (size_t)MEANS_B + (size_t)chunk * perb > ws_size) chunk >>= 1;

    unsigned short* MEANSp = (unsigned short*)(ws + MEANS_B);
    unsigned short* Y0p    = (unsigned short*)(ws + MEANS_B + (size_t)chunk * MEANS_PERB);
    unsigned short* YGp    = (unsigned short*)((unsigned char*)Y0p + (size_t)chunk * Y0_PERB);

    for (int cb = 0; cb < 16; cb += chunk) {
        b0_kernel<<<dim3(chunk * 256), dim3(256), 0, stream>>>(x, ws, Y0p, YGp, cb);
        b1_kernel<<<dim3(chunk * 64), dim3(512), 0, stream>>>(ws, Y0p, YGp, MEANSp);
        proj_kernel<<<dim3(chunk * 16), dim3(256), 0, stream>>>(MEANSp, ws, projb, (float*)d_out, cb * 2048);
    }
}

// Round 6
// 352.978 us; speedup vs baseline: 1.5160x; 1.0497x over previous
//
#include <hip/hip_runtime.h>
#include <hip/hip_bf16.h>
#include <stdint.h>

typedef __attribute__((ext_vector_type(8))) short bf16x8;
typedef __attribute__((ext_vector_type(4))) float f32x4;

#define EPSB 1e-5f

// ---------------- workspace byte offsets ----------------
#define W0TE_B   0u          // [64][192] bf16, k = tap*64 + c
#define W1SB_B   24576u      // [128][64] bf16
#define W1E_B    40960u      // [2][128][192] bf16
#define W1R_B    139264u     // [128][64] bf16
#define PROJW_B  155648u     // [128][128] bf16
#define WS0F_B   188416u     // [64][4] f32
#define WR0F_B   189440u     // [64][4] f32
#define BS0F_B   190464u     // [64] f32
#define CB0F_B   190720u     // [64] f32
#define BS1F_B   190976u     // [128] f32
#define CB1F_B   191488u     // [128] f32
#define SPT_B    192000u     // [17][8] float2 {a, k-as-uint-bits}
#define SCRATCH_B 193536u
#define Y0_PERB  4456448ull  // 2048*17*64*2

__device__ __forceinline__ float bf2f(unsigned int u16v) {
    union { unsigned int i; float f; } v; v.i = u16v << 16; return v.f;
}
__device__ __forceinline__ unsigned short f2bf(float f) {
    unsigned int x = __float_as_uint(f);
    x = x + 0x7fffu + ((x >> 16) & 1u);   // RNE
    return (unsigned short)(x >> 16);
}
__device__ __forceinline__ unsigned pk2(float a, float b) {
    union { __hip_bfloat162 h; unsigned u; } v;
    v.h = __float22bfloat162_rn(make_float2(a, b));
    return v.u;
}
__device__ __forceinline__ int div17(int p) { return (p * 241) >> 12; }  // valid p<=255

struct PrepArgs {
    const float *sw0,*sb0,*sg0,*sbb0,*sm0,*sv0;
    const float *tw0,*tb0,*tg0,*tbb0,*tm0,*tv0;
    const float *rw0,*rb0,*rg0,*rbb0,*rm0,*rv0;
    const float *sw1,*sb1,*sg1,*sbb1,*sm1,*sv1;
    const float *tw1,*tb1,*tg1,*tbb1,*tm1,*tv1;
    const float *rw1,*rb1,*rg1,*rbb1,*rm1,*rv1;
    const float *projw;
    const float *adj;
    unsigned char* ws;
};

__global__ void prep_kernel(PrepArgs a) {
    const int g = blockIdx.x * 256 + threadIdx.x;
    unsigned short* W0TE  = (unsigned short*)(a.ws + W0TE_B);
    unsigned short* W1SBp = (unsigned short*)(a.ws + W1SB_B);
    unsigned short* W1Ep  = (unsigned short*)(a.ws + W1E_B);
    unsigned short* W1Rp  = (unsigned short*)(a.ws + W1R_B);
    unsigned short* PROJW = (unsigned short*)(a.ws + PROJW_B);
    float* WS0F = (float*)(a.ws + WS0F_B);
    float* WR0F = (float*)(a.ws + WR0F_B);
    float* BS0F = (float*)(a.ws + BS0F_B);
    float* CB0F = (float*)(a.ws + CB0F_B);
    float* BS1F = (float*)(a.ws + BS1F_B);
    float* CB1F = (float*)(a.ws + CB1F_B);
    float2* SPT = (float2*)(a.ws + SPT_B);

    if (g < 64) {
        int o = g;
        float scs = a.sg0[o] / sqrtf(a.sv0[o] + EPSB);
        BS0F[o] = scs * (a.sb0[o] - a.sm0[o]) + a.sbb0[o];
        for (int c = 0; c < 4; c++) WS0F[o*4+c] = (c < 3) ? scs * a.sw0[o*3+c] : 0.f;
        float tct = a.tg0[o] / sqrtf(a.tv0[o] + EPSB);
        float rcr = a.rg0[o] / sqrtf(a.rv0[o] + EPSB);
        CB0F[o] = tct * (a.tb0[o] - a.tm0[o]) + a.tbb0[o]
                + rcr * (a.rb0[o] - a.rm0[o]) + a.rbb0[o];
        for (int c = 0; c < 4; c++) WR0F[o*4+c] = (c < 3) ? rcr * a.rw0[o*3+c] : 0.f;
    } else if (g < 192) {
        int o = g - 64;
        float scs = a.sg1[o] / sqrtf(a.sv1[o] + EPSB);
        BS1F[o] = scs * (a.sb1[o] - a.sm1[o]) + a.sbb1[o];
        float tct = a.tg1[o] / sqrtf(a.tv1[o] + EPSB);
        float rcr = a.rg1[o] / sqrtf(a.rv1[o] + EPSB);
        CB1F[o] = tct * (a.tb1[o] - a.tm1[o]) + a.tbb1[o]
                + rcr * (a.rb1[o] - a.rm1[o]) + a.rbb1[o];
    } else if (g < 12480) {                   // W0TE: 64*192
        int idx = g - 192;
        int o = idx / 192, k = idx % 192, tap = k >> 6, c = k & 63;
        float tct = a.tg0[o] / sqrtf(a.tv0[o] + EPSB);
        W0TE[o*192 + k] = f2bf(tct * a.tw0[(o*64 + c)*3 + tap]);
    } else if (g < 20672) {                   // W1SB: 128*64
        int idx = g - 12480;
        int o = idx >> 6, c = idx & 63;
        float scs = a.sg1[o] / sqrtf(a.sv1[o] + EPSB);
        W1SBp[o*64 + c] = f2bf(scs * a.sw1[o*64 + c]);
    } else if (g < 69824) {                   // W1E: 2*128*192
        int idx = g - 20672;
        int h = idx / 24576, r = idx % 24576;
        int o = r / 192, k = r % 192, tap = k >> 6, c = (h << 6) + (k & 63);
        float tct = a.tg1[o] / sqrtf(a.tv1[o] + EPSB);
        W1Ep[(h*128 + o)*192 + k] = f2bf(tct * a.tw1[(o*128 + c)*3 + tap]);
    } else if (g < 78016) {                   // W1R: 128*64
        int idx = g - 69824;
        int o = idx >> 6, c = idx & 63;
        float rcr = a.rg1[o] / sqrtf(a.rv1[o] + EPSB);
        W1Rp[o*64 + c] = f2bf(rcr * a.rw1[o*64 + c]);
    } else if (g < 94400) {                   // PROJW: 128*128
        int idx = g - 78016;
        PROJW[idx] = f2bf(a.projw[idx]);
    } else if (g < 94417) {                   // sparse adj columns
        int j = g - 94400;
        int cnt = 0;
        for (int k = 0; k < 17; k++) {
            float v = a.adj[k*17 + j];
            if (v != 0.0f && cnt < 8) {
                SPT[j*8 + cnt] = make_float2(v, __uint_as_float((unsigned)k));
                cnt++;
            }
        }
        for (; cnt < 8; cnt++) SPT[j*8 + cnt] = make_float2(0.f, __uint_as_float(0u));
    }
}

// ---------------- block 0: 3 -> 64, T-tile 8; also emits yg = graphconv(y0) ----------------
__launch_bounds__(256, 3)
__global__ void b0_kernel(const float* __restrict__ x,
                          const unsigned char* __restrict__ ws,
                          unsigned short* __restrict__ Y0,
                          unsigned short* __restrict__ YG, int b0base) {
    __shared__ float xt[510];                 // [3][170]
    __shared__ float xg[510];
    __shared__ float2 sptA[136];              // offsets *4 (f32 rows)
    __shared__ float2 sptB[136];              // offsets *144 (bf16 [.][72] rows)
    __shared__ float Ws0s[256], Wr0s[256], bs0s[64], cb0s[64];
    __shared__ __align__(16) unsigned short s0[170*72];
    __shared__ __align__(16) unsigned short yst[136*72];

    const int tid = threadIdx.x;
    const int b_loc = blockIdx.x >> 8;
    const int b = b0base + b_loc;
    const int t0 = (blockIdx.x & 255) << 3;
    const int Pb = (t0 - 1) * 17;

    const int w = tid >> 6, l = tid & 63, lr = l & 15, lg = l >> 4;
    const int n = w*16 + lr;

    const unsigned short* W0TE = (const unsigned short*)(ws + W0TE_B);
    bf16x8 bfr[6];
    #pragma unroll
    for (int ks = 0; ks < 6; ks++)
        bfr[ks] = *(const bf16x8*)&W0TE[n*192 + ks*32 + lg*8];

    if (tid < 136) {
        float2 raw = ((const float2*)(ws + SPT_B))[tid];
        sptA[tid] = make_float2(raw.x, __uint_as_float(__float_as_uint(raw.y) * 4u));
        sptB[tid] = make_float2(raw.x, __uint_as_float(__float_as_uint(raw.y) * 144u));
    }
    Ws0s[tid] = ((const float*)(ws + WS0F_B))[tid];
    Wr0s[tid] = ((const float*)(ws + WR0F_B))[tid];
    if (tid < 64) {
        bs0s[tid] = ((const float*)(ws + BS0F_B))[tid];
        cb0s[tid] = ((const float*)(ws + CB0F_B))[tid];
    }
    #pragma unroll
    for (int it = 0; it < 2; it++) {          // x -> LDS
        int idx = tid + it*256;
        if (idx < 510) {
            int c = idx / 170, r = idx - c*170;
            int P = Pb + r;
            float v = 0.f;
            if (P >= 0 && P < 34816) v = x[(size_t)(b*3 + c)*34816 + P];
            xt[idx] = v;
        }
    }
    __syncthreads();
    #pragma unroll
    for (int it = 0; it < 2; it++) {          // sparse graph conv on x
        int idx = tid + it*256;
        if (idx < 510) {
            int c = idx / 170, r = idx - c*170;
            int j = r - 17*div17(r);
            const char* rowb = (const char*)&xt[c*170 + (r - j)];
            float acc = 0.f;
            #pragma unroll
            for (int i = 0; i < 8; i++) {
                float2 e = sptA[j*8 + i];
                acc += e.x * *(const float*)(rowb + __float_as_uint(e.y));
            }
            xg[idx] = acc;
        }
    }
    __syncthreads();
    #pragma unroll
    for (int it = 0; it < 11; it++) {         // s0 = relu(conv1x1(xg)), zero OOB rows
        int idx = tid + it*256;
        if (idx < 2720) {
            int r = idx >> 4, cg = idx & 15, o0 = cg*4;
            int P = Pb + r;
            uint2 pkv = make_uint2(0u, 0u);
            if (P >= 0 && P < 34816) {
                float a0 = xg[r], a1 = xg[170 + r], a2 = xg[340 + r];
                float v0 = fmaxf(bs0s[o0]   + Ws0s[(o0  )*4]*a0 + Ws0s[(o0  )*4+1]*a1 + Ws0s[(o0  )*4+2]*a2, 0.f);
                float v1 = fmaxf(bs0s[o0+1] + Ws0s[(o0+1)*4]*a0 + Ws0s[(o0+1)*4+1]*a1 + Ws0s[(o0+1)*4+2]*a2, 0.f);
                float v2 = fmaxf(bs0s[o0+2] + Ws0s[(o0+2)*4]*a0 + Ws0s[(o0+2)*4+1]*a1 + Ws0s[(o0+2)*4+2]*a2, 0.f);
                float v3 = fmaxf(bs0s[o0+3] + Ws0s[(o0+3)*4]*a0 + Ws0s[(o0+3)*4+1]*a1 + Ws0s[(o0+3)*4+2]*a2, 0.f);
                pkv.x = pk2(v0, v1); pkv.y = pk2(v2, v3);
            }
            *(uint2*)&s0[r*72 + o0] = pkv;
        }
    }
    __syncthreads();
    {   // tconv GEMM + residual -> yst
        const float wr0 = Wr0s[n*4], wr1 = Wr0s[n*4+1], wr2 = Wr0s[n*4+2];
        const float cbn = cb0s[n];
        for (int mb = 0; mb < 9; mb++) {
            const int ra = mb*16 + lr;
            f32x4 acc = {0.f, 0.f, 0.f, 0.f};
            #pragma unroll
            for (int ks = 0; ks < 6; ks++) {
                int row = ra + (ks >> 1)*17; if (row > 169) row = 169;
                const int c0 = ((ks & 1) << 5) + lg*8;
                acc = __builtin_amdgcn_mfma_f32_16x16x32_bf16(
                    *(const bf16x8*)&s0[row*72 + c0], bfr[ks], acc, 0, 0, 0);
            }
            const int mbase = mb*16 + lg*4;
            #pragma unroll
            for (int i = 0; i < 4; i++) {
                const int m = mbase + i;
                if (m < 136) {
                    float v = acc[i] + cbn + wr0*xt[m+17] + wr1*xt[170+m+17] + wr2*xt[340+m+17];
                    yst[m*72 + n] = f2bf(fmaxf(v, 0.f));
                }
            }
        }
    }
    __syncthreads();
    #pragma unroll
    for (int it = 0; it < 5; it++) {          // Y0 store (contiguous in m)
        int idx = tid + it*256;
        if (idx < 1088) {
            int m = idx >> 3, seg = idx & 7;
            uint4 v = *(const uint4*)&yst[m*72 + seg*8];
            *(uint4*)&Y0[((size_t)b_loc*34816 + t0*17 + m)*64 + seg*8] = v;
        }
    }
    #pragma unroll
    for (int it = 0; it < 9; it++) {          // yg = graphconv(yst), reg->global
        int idx = tid + it*256;
        if (idx < 2176) {
            int p = idx >> 4, cg = idx & 15;
            int j = p - 17*div17(p);
            const char* rowb = (const char*)yst + (p - j)*144 + cg*8;
            float a0=0.f, a1=0.f, a2=0.f, a3=0.f;
            #pragma unroll
            for (int i = 0; i < 8; i++) {
                float2 e = sptB[j*8 + i];
                uint2 u = *(const uint2*)(rowb + __float_as_uint(e.y));
                a0 += e.x * __uint_as_float(u.x << 16);
                a1 += e.x * __uint_as_float(u.x & 0xffff0000u);
                a2 += e.x * __uint_as_float(u.y << 16);
                a3 += e.x * __uint_as_float(u.y & 0xffff0000u);
            }
            uint2 o; o.x = pk2(a0, a1); o.y = pk2(a2, a3);
            *(uint2*)&YG[((size_t)b_loc*34816 + t0*17 + p)*64 + cg*4] = o;
        }
    }
}

// ---------------- block 1: 64 -> 128 + mean + fused projection ----------------
__launch_bounds__(512, 2)
__global__ void b1_kernel(const unsigned char* __restrict__ ws,
                          const unsigned short* __restrict__ Y0,
                          const unsigned short* __restrict__ YG,
                          const float* __restrict__ projb,
                          float* __restrict__ outp, int b0base) {
    __shared__ __align__(16) unsigned short smem[36720];   // ybuf | ygbuf | s0buf, each [170][72]
    __shared__ __align__(16) unsigned short meansP[16*136];
    __shared__ float cb1s[128], bs1s[128];

    unsigned short* ybuf  = smem;
    unsigned short* ygbuf = smem + 12240;
    unsigned short* s0buf = smem + 24480;

    const int tid = threadIdx.x;
    const int b_loc = blockIdx.x >> 6;
    const int ck = blockIdx.x & 63;
    const int gb = b0base + b_loc;

    const unsigned short* W1SBp = (const unsigned short*)(ws + W1SB_B);
    const unsigned short* W1Ep  = (const unsigned short*)(ws + W1E_B);
    const unsigned short* W1Rp  = (const unsigned short*)(ws + W1R_B);
    const unsigned short* PROJW = (const unsigned short*)(ws + PROJW_B);

    const int w = tid >> 6, l = tid & 63, lr = l & 15, lg = l >> 4;
    const int n = w*16 + lr;
    const int sNt = w & 3, sMh = w >> 2;
    const int nloc_s = sNt*16 + lr;

    if (tid < 128) {
        cb1s[tid] = ((const float*)(ws + CB1F_B))[tid];
        bs1s[tid] = ((const float*)(ws + BS1F_B))[tid];
    }
    bf16x8 rb0 = *(const bf16x8*)&W1Rp[n*64 + lg*8];
    bf16x8 rb1 = *(const bf16x8*)&W1Rp[n*64 + 32 + lg*8];

    uint4 pf[5];
    auto PF = [&](int t0n) {
        const int Pbn = t0n*17 - 17;
        #pragma unroll
        for (int s = 0; s < 5; s++) {
            int idx = tid + s*512;
            uint4 v = make_uint4(0u,0u,0u,0u);
            if (idx < 1360) {                 // yg halo rows 0..169
                int p = idx >> 3, seg = idx & 7;
                int P = Pbn + p;
                if (P >= 0 && P < 34816)
                    v = *(const uint4*)&YG[((size_t)b_loc*34816 + P)*64 + seg*8];
            } else if (idx < 2448) {          // y0 center rows 0..135
                int p = (idx - 1360) >> 3, seg = (idx - 1360) & 7;
                v = *(const uint4*)&Y0[((size_t)b_loc*34816 + t0n*17 + p)*64 + seg*8];
            }
            pf[s] = v;
        }
    };
    PF(ck << 5);

    for (int tt = 0; tt < 4; tt++) {
        const int t0 = (ck << 5) + (tt << 3);
        const int Pb = (t0 - 1) * 17;
        const bool edge = (Pb < 0) || (Pb + 169 >= 34816);

        // ---- P0: commit prefetched tile ----
        #pragma unroll
        for (int s = 0; s < 5; s++) {
            int idx = tid + s*512;
            if (idx < 1360) {
                int p = idx >> 3, seg = idx & 7;
                *(uint4*)&ygbuf[p*72 + seg*8] = pf[s];
            } else if (idx < 2448) {
                int p = (idx - 1360) >> 3, seg = (idx - 1360) & 7;
                *(uint4*)&ybuf[(17 + p)*72 + seg*8] = pf[s];
            }
        }
        __syncthreads();

        // ---- P1: next-tile prefetch + residual GEMM + s1 h0 -> s0buf ----
        if (tt < 3) PF(t0 + 8);

        f32x4 tacc[9];
        #pragma unroll
        for (int mb = 0; mb < 9; mb++) {
            const int row = 17 + mb*16 + lr;
            f32x4 acc = {0.f, 0.f, 0.f, 0.f};
            acc = __builtin_amdgcn_mfma_f32_16x16x32_bf16(*(const bf16x8*)&ybuf[row*72 + lg*8],      rb0, acc, 0, 0, 0);
            acc = __builtin_amdgcn_mfma_f32_16x16x32_bf16(*(const bf16x8*)&ybuf[row*72 + 32 + lg*8], rb1, acc, 0, 0, 0);
            tacc[mb] = acc;
        }
        {
            bf16x8 sbA = *(const bf16x8*)&W1SBp[(nloc_s)*64 + lg*8];
            bf16x8 sbB = *(const bf16x8*)&W1SBp[(nloc_s)*64 + 32 + lg*8];
            const float bias = bs1s[nloc_s];
            const int mbS = sMh ? 6 : 0, mbE = sMh ? 11 : 6;
            if (!edge) {
                for (int mb = mbS; mb < mbE; mb++) {
                    int ra = mb*16 + lr; if (ra > 169) ra = 169;
                    f32x4 sa = {0.f, 0.f, 0.f, 0.f};
                    sa = __builtin_amdgcn_mfma_f32_16x16x32_bf16(*(const bf16x8*)&ygbuf[ra*72 + lg*8],      sbA, sa, 0, 0, 0);
                    sa = __builtin_amdgcn_mfma_f32_16x16x32_bf16(*(const bf16x8*)&ygbuf[ra*72 + 32 + lg*8], sbB, sa, 0, 0, 0);
                    const int mbase = mb*16 + lg*4;
                    #pragma unroll
                    for (int i = 0; i < 4; i++) {
                        int m = mbase + i;
                        if (m < 170) s0buf[m*72 + nloc_s] = f2bf(fmaxf(sa[i] + bias, 0.f));
                    }
                }
            } else {
                for (int mb = mbS; mb < mbE; mb++) {
                    int ra = mb*16 + lr; if (ra > 169) ra = 169;
                    f32x4 sa = {0.f, 0.f, 0.f, 0.f};
                    sa = __builtin_amdgcn_mfma_f32_16x16x32_bf16(*(const bf16x8*)&ygbuf[ra*72 + lg*8],      sbA, sa, 0, 0, 0);
                    sa = __builtin_amdgcn_mfma_f32_16x16x32_bf16(*(const bf16x8*)&ygbuf[ra*72 + 32 + lg*8], sbB, sa, 0, 0, 0);
                    const int mbase = mb*16 + lg*4;
                    #pragma unroll
                    for (int i = 0; i < 4; i++) {
                        int m = mbase + i;
                        if (m < 170) {
                            int P = Pb + m;
                            float v = (P >= 0 && P < 34816) ? fmaxf(sa[i] + bias, 0.f) : 0.f;
                            s0buf[m*72 + nloc_s] = f2bf(v);
                        }
                    }
                }
            }
        }
        __syncthreads();

        // ---- P2: tconv h0 (s0buf) + s1 h1 -> ybuf ----
        {
            bf16x8 bfh[6];
            #pragma unroll
            for (int ks = 0; ks < 6; ks++)
                bfh[ks] = *(const bf16x8*)&W1Ep[n*192 + ks*32 + lg*8];
            __builtin_amdgcn_s_setprio(1);
            #pragma unroll
            for (int mb = 0; mb < 9; mb++) {
                const int ma = mb*16 + lr;
                f32x4 acc = tacc[mb];
                #pragma unroll
                for (int ks = 0; ks < 6; ks++) {
                    int row = ma + (ks >> 1)*17; if (row > 169) row = 169;
                    const int c0 = ((ks & 1) << 5) + lg*8;
                    acc = __builtin_amdgcn_mfma_f32_16x16x32_bf16(
                        *(const bf16x8*)&s0buf[row*72 + c0], bfh[ks], acc, 0, 0, 0);
                }
                tacc[mb] = acc;
            }
            __builtin_amdgcn_s_setprio(0);
        }
        {
            bf16x8 sbA = *(const bf16x8*)&W1SBp[(64 + nloc_s)*64 + lg*8];
            bf16x8 sbB = *(const bf16x8*)&W1SBp[(64 + nloc_s)*64 + 32 + lg*8];
            const float bias = bs1s[64 + nloc_s];
            const int mbS = sMh ? 6 : 0, mbE = sMh ? 11 : 6;
            if (!edge) {
                for (int mb = mbS; mb < mbE; mb++) {
                    int ra = mb*16 + lr; if (ra > 169) ra = 169;
                    f32x4 sa = {0.f, 0.f, 0.f, 0.f};
                    sa = __builtin_amdgcn_mfma_f32_16x16x32_bf16(*(const bf16x8*)&ygbuf[ra*72 + lg*8],      sbA, sa, 0, 0, 0);
                    sa = __builtin_amdgcn_mfma_f32_16x16x32_bf16(*(const bf16x8*)&ygbuf[ra*72 + 32 + lg*8], sbB, sa, 0, 0, 0);
                    const int mbase = mb*16 + lg*4;
                    #pragma unroll
                    for (int i = 0; i < 4; i++) {
                        int m = mbase + i;
                        if (m < 170) ybuf[m*72 + nloc_s] = f2bf(fmaxf(sa[i] + bias, 0.f));
                    }
                }
            } else {
                for (int mb = mbS; mb < mbE; mb++) {
                    int ra = mb*16 + lr; if (ra > 169) ra = 169;
                    f32x4 sa = {0.f, 0.f, 0.f, 0.f};
                    sa = __builtin_amdgcn_mfma_f32_16x16x32_bf16(*(const bf16x8*)&ygbuf[ra*72 + lg*8],      sbA, sa, 0, 0, 0);
                    sa = __builtin_amdgcn_mfma_f32_16x16x32_bf16(*(const bf16x8*)&ygbuf[ra*72 + 32 + lg*8], sbB, sa, 0, 0, 0);
                    const int mbase = mb*16 + lg*4;
                    #pragma unroll
                    for (int i = 0; i < 4; i++) {
                        int m = mbase + i;
                        if (m < 170) {
                            int P = Pb + m;
                            float v = (P >= 0 && P < 34816) ? fmaxf(sa[i] + bias, 0.f) : 0.f;
                            ybuf[m*72 + nloc_s] = f2bf(v);
                        }
                    }
                }
            }
        }
        __syncthreads();

        // ---- P3: tconv h1 (ybuf) + in-register mean over J -> meansP ----
        {
            bf16x8 bfh[6];
            #pragma unroll
            for (int ks = 0; ks < 6; ks++)
                bfh[ks] = *(const bf16x8*)&W1Ep[(128 + n)*192 + ks*32 + lg*8];
            __builtin_amdgcn_s_setprio(1);
            #pragma unroll
            for (int mb = 0; mb < 9; mb++) {
                const int ma = mb*16 + lr;
                f32x4 acc = tacc[mb];
                #pragma unroll
                for (int ks = 0; ks < 6; ks++) {
                    int row = ma + (ks >> 1)*17; if (row > 169) row = 169;
                    const int c0 = ((ks & 1) << 5) + lg*8;
                    acc = __builtin_amdgcn_mfma_f32_16x16x32_bf16(
                        *(const bf16x8*)&ybuf[row*72 + c0], bfh[ks], acc, 0, 0, 0);
                }
                tacc[mb] = acc;
            }
            __builtin_amdgcn_s_setprio(0);
        }
        {
            const float cb = cb1s[n];
            float mv0 = 0.f, mv1 = 0.f;
            #pragma unroll
            for (int t = 0; t < 8; t++) {
                float s = 0.f;
                #pragma unroll
                for (int mb = 0; mb < 9; mb++) {
                    #pragma unroll
                    for (int i = 0; i < 4; i++) {
                        const int mlo = mb*16 + i;          // lane's m = mlo + lg*4
                        if (mlo + 12 >= t*17 && mlo <= t*17 + 16 && mlo < 136) {
                            int m = mlo + lg*4;
                            bool in = (m >= t*17) && (m <= t*17 + 16) && (m < 136);
                            float v = fmaxf(tacc[mb][i] + cb, 0.f);
                            s += in ? v : 0.f;
                        }
                    }
                }
                s += __shfl_xor(s, 16, 64);
                s += __shfl_xor(s, 32, 64);
                float mval = s * (1.f / 17.f);
                if (t == lg)     mv0 = mval;
                if (t == lg + 4) mv1 = mval;
            }
            const int mrow = (tt & 1) * 8;
            meansP[(mrow + lg)*136 + n]     = f2bf(mv0);
            meansP[(mrow + 4 + lg)*136 + n] = f2bf(mv1);
        }
        __syncthreads();

        // ---- P4 (every 2nd tile): projection of 16 t-rows -> d_out ----
        if (tt & 1) {
            const int et = w;                 // e-block 0..7
            bf16x8 pw[4];
            #pragma unroll
            for (int kf = 0; kf < 4; kf++)
                pw[kf] = *(const bf16x8*)&PROJW[(et*16 + lr)*128 + kf*32 + lg*8];
            f32x4 pa = {0.f, 0.f, 0.f, 0.f};
            #pragma unroll
            for (int kf = 0; kf < 4; kf++)
                pa = __builtin_amdgcn_mfma_f32_16x16x32_bf16(
                    *(const bf16x8*)&meansP[lr*136 + kf*32 + lg*8], pw[kf], pa, 0, 0, 0);
            const float pb = projb[et*16 + lr];
            const int tbase = ck*32 + (tt - 1)*8;
            #pragma unroll
            for (int i = 0; i < 4; i++) {
                const int m = lg*4 + i;
                outp[((size_t)gb*2048 + tbase + m)*128 + et*16 + lr] = pa[i] + pb;
            }
        }
    }
}

extern "C" void kernel_launch(void* const* d_in, const int* in_sizes, int n_in,
                              void* d_out, int out_size, void* d_ws, size_t ws_size,
                              hipStream_t stream) {
    const float* x     = (const float*)d_in[0];
    const float* adj   = (const float*)d_in[1];
    const float* projb = (const float*)d_in[39];
    unsigned char* ws  = (unsigned char*)d_ws;

    PrepArgs pa;
    pa.sw0 = (const float*)d_in[2];  pa.sb0  = (const float*)d_in[3];
    pa.sg0 = (const float*)d_in[4];  pa.sbb0 = (const float*)d_in[5];
    pa.sm0 = (const float*)d_in[6];  pa.sv0  = (const float*)d_in[7];
    pa.tw0 = (const float*)d_in[8];  pa.tb0  = (const float*)d_in[9];
    pa.tg0 = (const float*)d_in[10]; pa.tbb0 = (const float*)d_in[11];
    pa.tm0 = (const float*)d_in[12]; pa.tv0  = (const float*)d_in[13];
    pa.rw0 = (const float*)d_in[14]; pa.rb0  = (const float*)d_in[15];
    pa.rg0 = (const float*)d_in[16]; pa.rbb0 = (const float*)d_in[17];
    pa.rm0 = (const float*)d_in[18]; pa.rv0  = (const float*)d_in[19];
    pa.sw1 = (const float*)d_in[20]; pa.sb1  = (const float*)d_in[21];
    pa.sg1 = (const float*)d_in[22]; pa.sbb1 = (const float*)d_in[23];
    pa.sm1 = (const float*)d_in[24]; pa.sv1  = (const float*)d_in[25];
    pa.tw1 = (const float*)d_in[26]; pa.tb1  = (const float*)d_in[27];
    pa.tm1 = (const float*)d_in[30]; pa.tbb1 = (const float*)d_in[29];
    pa.tg1 = (const float*)d_in[28];
    pa.tv1  = (const float*)d_in[31];
    pa.rw1 = (const float*)d_in[32]; pa.rb1  = (const float*)d_in[33];
    pa.rg1 = (const float*)d_in[34]; pa.rbb1 = (const float*)d_in[35];
    pa.rm1 = (const float*)d_in[36]; pa.rv1  = (const float*)d_in[37];
    pa.projw = (const float*)d_in[38];
    pa.adj = adj;
    pa.ws = ws;

    prep_kernel<<<dim3(369), dim3(256), 0, stream>>>(pa);

    // per-batch scratch: Y0 + YG
    const size_t perb = 2ull * Y0_PERB;
    int chunk = 16;
    while (chunk > 1 && (size_t)SCRATCH_B + (size_t)chunk * perb > ws_size) chunk >>= 1;

    unsigned short* Y0p = (unsigned short*)(ws + SCRATCH_B);
    unsigned short* YGp = (unsigned short*)((unsigned char*)Y0p + (size_t)chunk * Y0_PERB);

    for (int cb = 0; cb < 16; cb += chunk) {
        b0_kernel<<<dim3(chunk * 256), dim3(256), 0, stream>>>(x, ws, Y0p, YGp, cb);
        b1_kernel<<<dim3(chunk * 64), dim3(512), 0, stream>>>(ws, Y0p, YGp, projb, (float*)d_out, cb);
    }
}